// Round 14
// baseline (1398.478 us; speedup 1.0000x reference)
//
#include <hip/hip_runtime.h>
#include <math.h>

typedef unsigned short u16;
typedef unsigned int uint;
typedef __bf16 bf16x8 __attribute__((ext_vector_type(8)));
typedef unsigned short u16x8 __attribute__((ext_vector_type(8)));
typedef float f32x4 __attribute__((ext_vector_type(4)));

#define HWQ 16384
#define PI_F 3.14159265358979323846f

// canonical (bf16) input offsets inside ws
#define C_X     0
#define C_TOK   262144
#define C_QW    1310720
#define C_QB    1376256
#define C_WQ    1376768
#define C_WKV   1442304
#define C_WO    1704448
#define C_BO    1769984
#define C_BWW   1770496
#define C_BWB   1967104
#define C_MODW  1968640
#define C_MODB  2755072
#define C_HVW   2756608
#define C_HVB   3280896
#define C_OUTW  3281920
#define C_OUTB  3286528
#define C_TOTAL 3286537
#define CANON_PAD 3286544

// WT (transposed weights) element offsets (relative to WT base)
// QWT/WQT/WOT/BWT: [col][K] layout (used by k_query/k_attn).
// MODT/HVT: K-BLOCKED layout [kblk][col][32] (used by k_bands3).
#define QWT_OFF  0
#define WQT_OFF  65536
#define WOT_OFF  131072
#define BWT_OFF  196608
#define MODT_OFF 393216
#define HVT_OFF  1179648

struct SrcPtrs { const void* p[16]; };

__device__ __forceinline__ float bs2f(u16 u){
  unsigned v = ((unsigned)u) << 16; float f; __builtin_memcpy(&f, &v, 4); return f;
}
__device__ __forceinline__ u16 f2bs(float f){
  unsigned v; __builtin_memcpy(&v, &f, 4);
  v = (v + 0x7fffu + ((v >> 16) & 1u)) >> 16;
  return (u16)v;
}
__device__ __forceinline__ f32x4 mfma16(bf16x8 a, bf16x8 b, f32x4 c){
  return __builtin_amdgcn_mfma_f32_16x16x32_bf16(a, b, c, 0, 0, 0);
}
__device__ __forceinline__ bf16x8 ld8(const u16* p){ return *(const bf16x8*)p; }

// ---------------- dtype detect ----------------
__global__ void k_detect(const u16* qb_raw, unsigned* flag){
  __shared__ int cnt[256];
  int t = threadIdx.x;
  u16 u = qb_raw[2*t];
  int e = (u >> 7) & 0xFF;
  cnt[t] = (e >= 126) ? 1 : 0;
  __syncthreads();
  for (int s = 128; s > 0; s >>= 1){
    if (t < s) cnt[t] += cnt[t + s];
    __syncthreads();
  }
  if (t == 0) *flag = (cnt[0] >= 16) ? 1u : 0u;
}

// ---------------- convert inputs to canonical bf16 ----------------
__global__ __launch_bounds__(256) void k_convert(SrcPtrs sp, const unsigned* flag, u16* canon){
  const int offs[17] = {C_X,C_TOK,C_QW,C_QB,C_WQ,C_WKV,C_WO,C_BO,C_BWW,C_BWB,
                        C_MODW,C_MODB,C_HVW,C_HVB,C_OUTW,C_OUTB,C_TOTAL};
  int e = blockIdx.x * 256 + threadIdx.x;
  if (e >= C_TOTAL) return;
  int seg = 0;
  for (int i = 1; i < 16; i++) if (e >= offs[i]) seg = i;
  int local = e - offs[seg];
  if (*flag) canon[e] = f2bs(((const float*)sp.p[seg])[local]);
  else       canon[e] = ((const u16*)sp.p[seg])[local];
}

// ---------------- weight transpose ----------------
// bid < 384: [col][K] layout (query/attn weights).
// bid >= 384 (mod/hv): K-BLOCKED [kblk][col][32]: elem(col,k) at (k>>5)*16384 + col*32 + (k&31).
__global__ __launch_bounds__(256) void k_tr(const u16* canon, u16* WT){
  __shared__ u16 tile[32][33];
  int bid = blockIdx.x, t = threadIdx.x;
  const u16* src; u16* dst; int K, N, tl;
  bool kblk = (bid >= 384);
  if (bid < 384){
    int m = bid >> 6; tl = bid & 63;
    if (m == 0){ src = canon + C_QW;  dst = WT + QWT_OFF; K = 128; N = 512; }
    else if (m == 1){ src = canon + C_WQ; dst = WT + WQT_OFF; K = 512; N = 128; }
    else if (m == 2){ src = canon + C_WO; dst = WT + WOT_OFF; K = 128; N = 512; }
    else { src = canon + C_BWW + (m-3)*65536; dst = WT + BWT_OFF + (m-3)*65536; K = 128; N = 512; }
  } else if (bid < 1152){
    int m = (bid - 384) >> 8; tl = (bid - 384) & 255;
    src = canon + C_MODW + m*262144; dst = WT + MODT_OFF + m*262144; K = 512; N = 512;
  } else {
    int m = (bid - 1152) >> 8; tl = (bid - 1152) & 255;
    src = canon + C_HVW + m*262144; dst = WT + HVT_OFF + m*262144; K = 512; N = 512;
  }
  int kt = K >> 5;
  int k0 = (tl % kt) * 32, n0 = (tl / kt) * 32;
  int tx = t & 31, ty = t >> 5;
  for (int r = 0; r < 4; r++)
    tile[ty + r*8][tx] = src[(size_t)(k0 + ty + r*8) * N + n0 + tx];
  __syncthreads();
  if (!kblk){
    for (int r = 0; r < 4; r++)
      dst[(size_t)(n0 + ty + r*8) * K + k0 + tx] = tile[tx][ty + r*8];
  } else {
    u16* d2 = dst + (size_t)(k0 >> 5)*16384;
    for (int r = 0; r < 4; r++)
      d2[(n0 + ty + r*8)*32 + tx] = tile[tx][ty + r*8];
  }
}

// ---------------- kv = tokens @ Wkv ----------------
__global__ __launch_bounds__(256) void k_kv(const u16* canon, u16* kpart, u16* vT){
  int b = blockIdx.x >> 8, kk = blockIdx.x & 255, t = threadIdx.x;
  const u16* tok = canon + C_TOK;
  const u16* Wkv = canon + C_WKV;
  __shared__ float tk[512];
  const u16* tr = tok + ((size_t)(b*256 + kk)) * 512;
  tk[t] = bs2f(tr[t]); tk[t+256] = bs2f(tr[t+256]);
  __syncthreads();
  float acc = 0.f;
  for (int k = 0; k < 512; k++) acc += tk[k] * bs2f(Wkv[k*256 + t]);
  if (t < 128) kpart[((size_t)(b*256 + kk))*128 + t] = f2bs(acc);
  else vT[((size_t)b*128 + (t-128))*256 + kk] = f2bs(acc);
}

// ---------------- per-query: gamma -> xq -> qvec ; h_l bands ----------------
__global__ __launch_bounds__(256) void k_query(const u16* canon, const float* xraw,
      const unsigned* flag, const u16* WT, u16* qvecB, u16* hlB){
  int t = threadIdx.x, q0 = blockIdx.x * 16;
  const u16* q_b = canon + C_QB;
  const u16* bw_b= canon + C_BWB;
  int lane = t & 63, wv = t >> 6, l15 = lane & 15, q4 = lane >> 4;
  __shared__ __align__(16) u16 g[16*136];
  __shared__ __align__(16) u16 xql[16*520];
  __shared__ float cco[32];
  __shared__ float omg[32];
  for (int e = t; e < 16*136; e += 256) g[e] = 0;
  for (int e = t; e < 16*520; e += 256) xql[e] = 0;
  if (t < 32) cco[t] = (*flag) ? xraw[q0*2 + t] : bs2f(canon[C_X + q0*2 + t]);
  if (t < 32) omg[t] = (float)pow(10.0, 1.0 + t * ((2.1072099696478683 - 1.0)/31.0));
  __syncthreads();
  for (int i = 0; i < 8; i++){
    int id = i*256 + t, qi = id >> 7, f = id & 127;
    int d = f >> 6, r = f & 63, fi = r & 31;
    float arg = PI_F * cco[qi*2 + d] * omg[fi];
    g[qi*136 + f] = f2bs((r < 32) ? sinf(arg) : cosf(arg));
  }
  __syncthreads();
  { // xq = relu(g @ q_W + q_b) -> xql
    const u16* Bm = WT + QWT_OFF;
    for (int nt = 0; nt < 8; nt++){
      f32x4 acc = {0.f,0.f,0.f,0.f};
      int c = wv*128 + nt*16 + l15;
      for (int ks = 0; ks < 4; ks++){
        bf16x8 a  = ld8(g + l15*136 + ks*32 + q4*8);
        bf16x8 bb = ld8(Bm + (size_t)c*128 + ks*32 + q4*8);
        acc = mfma16(a, bb, acc);
      }
      float qb = bs2f(q_b[c]);
      for (int rg = 0; rg < 4; rg++){
        int row = q4*4 + rg;
        xql[row*520 + c] = f2bs(fmaxf(acc[rg] + qb, 0.f));
      }
    }
  }
  __syncthreads();
  { // qvec = xq @ Wq -> stage in g -> coalesced store
    const u16* Bm = WT + WQT_OFF;
    for (int nh = 0; nh < 2; nh++){
      f32x4 acc = {0.f,0.f,0.f,0.f};
      int c = wv*32 + nh*16 + l15;
      for (int ks = 0; ks < 16; ks++){
        bf16x8 a  = ld8(xql + l15*520 + ks*32 + q4*8);
        bf16x8 bb = ld8(Bm + (size_t)c*512 + ks*32 + q4*8);
        acc = mfma16(a, bb, acc);
      }
      for (int rg = 0; rg < 4; rg++)
        g[(q4*4 + rg)*128 + c] = f2bs(acc[rg]);
    }
    __syncthreads();
    {
      int rr = t >> 4, cc = (t & 15)*8;
      *(u16x8*)(qvecB + (size_t)(q0 + rr)*128 + cc) = *(const u16x8*)(g + rr*128 + cc);
    }
  }
  const double LG[3] = {1.2041199826559248, 1.8061799739838869, 2.4082399653118496};
  for (int ib = 0; ib < 3; ib++){
    __syncthreads();
    if (t < 32) omg[t] = (float)pow(10.0, 1.0 + t * ((LG[ib] - 1.0)/31.0));
    __syncthreads();
    for (int i = 0; i < 8; i++){
      int id = i*256 + t, qi = id >> 7, f = id & 127;
      int d = f >> 6, r = f & 63, fi = r & 31;
      float arg = PI_F * cco[qi*2 + d] * omg[fi];
      g[qi*136 + f] = f2bs((r < 32) ? sinf(arg) : cosf(arg));
    }
    __syncthreads();
    const u16* Bm = WT + BWT_OFF + ib*65536;
    for (int nt = 0; nt < 8; nt++){
      f32x4 acc = {0.f,0.f,0.f,0.f};
      int c = wv*128 + nt*16 + l15;
      for (int ks = 0; ks < 4; ks++){
        bf16x8 a  = ld8(g + l15*136 + ks*32 + q4*8);
        bf16x8 bb = ld8(Bm + (size_t)c*128 + ks*32 + q4*8);
        acc = mfma16(a, bb, acc);
      }
      float bias = bs2f(bw_b[ib*512 + c]);
      for (int rg = 0; rg < 4; rg++)
        xql[(q4*4 + rg)*520 + c] = f2bs(fmaxf(acc[rg] + bias, 0.f));
    }
    __syncthreads();
    for (int it = 0; it < 4; it++){
      int rr = it*4 + (t >> 6), cc = (t & 63)*8;
      *(u16x8*)(hlB + ((size_t)ib*HWQ + q0 + rr)*512 + cc) = *(const u16x8*)(xql + rr*520 + cc);
    }
  }
}

// ---------------- attention + mod projection (f32 softmax, staged store) ----------------
// modB is stored FRAGMENT-LINEAR per 64-row group:
//   row gr=(q*8+b): rgp=q>>3, r=(q&7)*8+b; elem c:
//   off = rgp*32768 + (c>>5)*2048 + (r>>4)*512 + ((c>>3)&3)*128 + (r&15)*8 + (c&7)
__global__ __launch_bounds__(256) void k_attn(const u16* canon, const float* xraw,
      const unsigned* flag, const u16* qvecB, const u16* kpart, const u16* vT,
      const u16* WT, u16* modB){
  int t = threadIdx.x;
  int b = blockIdx.x & 7, qt = blockIdx.x >> 3, q0 = qt*32;
  const u16* bo = canon + C_BO;
  int lane = t & 63, wv = t >> 6, l15 = lane & 15, q4 = lane >> 4;
  __shared__ __align__(16) u16 ql[32*136];
  __shared__ __align__(16) u16 pl[32*264];
  __shared__ __align__(16) float pf[32*264];
  __shared__ __align__(16) u16 ot[32*136];
  __shared__ float tqs[32];
  __shared__ float red[256];
  __shared__ float rst[32];
  for (int e = t; e < 32*136; e += 256){ ql[e] = 0; ot[e] = 0; }
  for (int e = t; e < 32*264; e += 256) pl[e] = 0;
  __syncthreads();
  for (int i = 0; i < 16; i++){
    int id = i*256 + t, qi = id >> 7, c = id & 127;
    ql[qi*136 + c] = qvecB[(size_t)(q0 + qi)*128 + c];
  }
  if (t < 32){
    float c0, c1;
    if (*flag){ c0 = xraw[(q0+t)*2]; c1 = xraw[(q0+t)*2 + 1]; }
    else { c0 = bs2f(canon[C_X + (q0+t)*2]); c1 = bs2f(canon[C_X + (q0+t)*2 + 1]); }
    int rr = (int)(c0*16.f), cc = (int)(c1*16.f);
    tqs[t] = (float)(rr*16 + cc) * (1.f/256.f);
  }
  __syncthreads();
  for (int h = 0; h < 2; h++){
    f32x4 sac[2][4];
    for (int mt = 0; mt < 2; mt++) for (int nt = 0; nt < 4; nt++) sac[mt][nt] = (f32x4){0.f,0.f,0.f,0.f};
    const u16* kb = kpart + (size_t)b*256*128 + h*64;
    for (int ks = 0; ks < 2; ks++){
      bf16x8 a0 = ld8(ql + l15*136 + h*64 + ks*32 + q4*8);
      bf16x8 a1 = ld8(ql + (16+l15)*136 + h*64 + ks*32 + q4*8);
      for (int nt = 0; nt < 4; nt++){
        int kk = wv*64 + nt*16 + l15;
        bf16x8 bb = ld8(kb + (size_t)kk*128 + ks*32 + q4*8);
        sac[0][nt] = mfma16(a0, bb, sac[0][nt]);
        sac[1][nt] = mfma16(a1, bb, sac[1][nt]);
      }
    }
    for (int mt = 0; mt < 2; mt++) for (int nt = 0; nt < 4; nt++){
      int kk = wv*64 + nt*16 + l15;
      float pos = ((float)kk + 0.5f) * (1.f/256.f);
      for (int rg = 0; rg < 4; rg++){
        int row = mt*16 + q4*4 + rg;
        float dd = tqs[row] - pos;
        pf[row*264 + kk] = sac[mt][nt][rg]*0.125f - 10.f*dd*dd;
      }
    }
    __syncthreads();
    {
      int r = t >> 3, i = t & 7;
      float* pr = pf + r*264 + i*32;
      u16* po = pl + r*264 + i*32;
      float m = -1e30f;
      for (int j = 0; j < 32; j++) m = fmaxf(m, pr[j]);
      red[t] = m;
      __syncthreads();
      if (t < 32){ float mm = red[t*8];
        for (int j = 1; j < 8; j++) mm = fmaxf(mm, red[t*8+j]);
        rst[t] = mm; }
      __syncthreads();
      float mm = rst[r], sum = 0.f;
      for (int j = 0; j < 32; j++){ float e = expf(pr[j] - mm); pr[j] = e; sum += e; }
      red[t] = sum;
      __syncthreads();
      if (t < 32){ float ss = 0.f;
        for (int j = 0; j < 8; j++) ss += red[t*8+j];
        rst[t] = 1.f/ss; }
      __syncthreads();
      float inv = rst[r];
      for (int j = 0; j < 32; j++) po[j] = f2bs(pr[j] * inv);
    }
    __syncthreads();
    f32x4 oac[2] = {(f32x4){0.f,0.f,0.f,0.f}, (f32x4){0.f,0.f,0.f,0.f}};
    const u16* vb = vT + ((size_t)b*128 + h*64)*256;
    int dl = wv*16 + l15;
    for (int ks = 0; ks < 8; ks++){
      bf16x8 a0 = ld8(pl + l15*264 + ks*32 + q4*8);
      bf16x8 a1 = ld8(pl + (16+l15)*264 + ks*32 + q4*8);
      bf16x8 bb = ld8(vb + (size_t)dl*256 + ks*32 + q4*8);
      oac[0] = mfma16(a0, bb, oac[0]);
      oac[1] = mfma16(a1, bb, oac[1]);
    }
    for (int mt = 0; mt < 2; mt++) for (int rg = 0; rg < 4; rg++){
      int row = mt*16 + q4*4 + rg;
      ot[row*136 + h*64 + dl] = f2bs(oac[mt][rg]);
    }
    __syncthreads();
  }
  u16* stg = (u16*)pf;
  const u16* wob = WT + WOT_OFF;
  for (int nt = 0; nt < 8; nt++){
    f32x4 mac[2] = {(f32x4){0.f,0.f,0.f,0.f}, (f32x4){0.f,0.f,0.f,0.f}};
    int c = wv*128 + nt*16 + l15;
    for (int ks = 0; ks < 4; ks++){
      bf16x8 a0 = ld8(ot + l15*136 + ks*32 + q4*8);
      bf16x8 a1 = ld8(ot + (16+l15)*136 + ks*32 + q4*8);
      bf16x8 bb = ld8(wob + (size_t)c*128 + ks*32 + q4*8);
      mac[0] = mfma16(a0, bb, mac[0]);
      mac[1] = mfma16(a1, bb, mac[1]);
    }
    float bv = bs2f(bo[c]);
    for (int mt = 0; mt < 2; mt++) for (int rg = 0; rg < 4; rg++){
      int row = mt*16 + q4*4 + rg;
      stg[row*512 + c] = f2bs(mac[mt][rg] + bv);
    }
  }
  __syncthreads();
  for (int it = 0; it < 8; it++){
    int rr = it*4 + (t >> 6), cc = (t & 63)*8;
    int q = q0 + rr;
    int rgp = q >> 3, r = (q & 7)*8 + b;
    size_t off = (size_t)rgp*32768 + (size_t)(cc >> 5)*2048 + (size_t)(r >> 4)*512
               + (size_t)((cc >> 3) & 3)*128 + (size_t)(r & 15)*8;
    *(u16x8*)(modB + off) = *(const u16x8*)(stg + rr*512 + cc);
  }
}

// ================= k_bands3 v14: M=128 rows/block — halve B-weight restreaming =================
// Calibrated model (v13): per-CU cycles ~= MFMA 366k + B-L1-stream 320k + epilogue
// VALU + latency. B-stream ~ 1/M. v14: 1024 blocks x 128 rows (2 consecutive
// 64-row modB groups), 8 waves x 64 cols, 5 single-acc phases (acc[8][4] = 128
// AGPR; dual-acc fusion impossible at this M). A read DIRECT from global
// (fragment-linear modB: contiguous 1KB loads, 8 waves share -> L1). XL holds the
// 128-row residual in fragment-linear form (conflict-free); X1/X3 same-thread
// bf16 RMW (v10 discipline). launch_bounds(512,2): 256-reg cap, no spill expected.
// LDS: XL 128K + pscr 12K + totrow 1.5K = 141.8 KB (1 block/CU).

// Fragment-linear XL (128 rows): elem(row, c) at
//   (c>>5)*4096 + (row>>4)*512 + ((c>>3)&3)*128 + (row&15)*8 + (c&7)
#define XLI(row, c) (((c) >> 5)*4096 + (((row) >> 4))*512 + ((((c) >> 3) & 3))*128 + (((row) & 15))*8 + ((c) & 7))

#define ZACC for (int mt = 0; mt < 8; mt++) for (int nt = 0; nt < 4; nt++) acc[mt][nt] = (f32x4){0.f,0.f,0.f,0.f};

// A direct from global (two fragment-linear 64-row modB groups), B global K-blocked.
#define GEMMG(Bgl)                                                               \
  { ZACC                                                                         \
    const u16* bptr = (Bgl) + (size_t)(w*64 + l15)*32 + q4*8;                    \
    _Pragma("unroll 1")                                                          \
    for (int ks = 0; ks < 16; ks++){                                             \
      bf16x8 b0 = ld8(bptr + ks*16384 +    0);                                   \
      bf16x8 b1 = ld8(bptr + ks*16384 +  512);                                   \
      bf16x8 b2 = ld8(bptr + ks*16384 + 1024);                                   \
      bf16x8 b3 = ld8(bptr + ks*16384 + 1536);                                   \
      for (int g = 0; g < 2; g++){                                               \
        const u16* ap = (g ? ag1 : ag0) + ks*2048;                               \
        for (int mtl = 0; mtl < 4; mtl++){                                       \
          bf16x8 af = ld8(ap + mtl*512);                                         \
          int mt = g*4 + mtl;                                                    \
          acc[mt][0] = mfma16(af, b0, acc[mt][0]);                               \
          acc[mt][1] = mfma16(af, b1, acc[mt][1]);                               \
          acc[mt][2] = mfma16(af, b2, acc[mt][2]);                               \
          acc[mt][3] = mfma16(af, b3, acc[mt][3]);                               \
        }                                                                        \
      } } }

// A from XL (fragment-linear 128 rows), B global K-blocked.
#define GEMML(Bgl)                                                               \
  { ZACC                                                                         \
    const u16* bptr = (Bgl) + (size_t)(w*64 + l15)*32 + q4*8;                    \
    const u16* ap0  = XL + q4*128 + l15*8;                                       \
    _Pragma("unroll 1")                                                          \
    for (int ks = 0; ks < 16; ks++){                                             \
      bf16x8 b0 = ld8(bptr + ks*16384 +    0);                                   \
      bf16x8 b1 = ld8(bptr + ks*16384 +  512);                                   \
      bf16x8 b2 = ld8(bptr + ks*16384 + 1024);                                   \
      bf16x8 b3 = ld8(bptr + ks*16384 + 1536);                                   \
      for (int mt = 0; mt < 8; mt++){                                            \
        bf16x8 af = ld8(ap0 + ks*4096 + mt*512);                                 \
        acc[mt][0] = mfma16(af, b0, acc[mt][0]);                                 \
        acc[mt][1] = mfma16(af, b1, acc[mt][1]);                                 \
        acc[mt][2] = mfma16(af, b2, acc[mt][2]);                                 \
        acc[mt][3] = mfma16(af, b3, acc[mt][3]);                                 \
      } } }

#define PROJ_REDUCE                                                              \
  __syncthreads();                                                               \
  if (t < 384){ float s = 0.f;                                                   \
    for (int w2 = 0; w2 < 8; w2++) s += pscr[w2*384 + t];                        \
    totrow[t] += s; }                                                            \
  __syncthreads();

__global__ __launch_bounds__(512, 2) void k_bands3(const u16* canon, const u16* modB,
      const u16* WT, const u16* hlB, const unsigned* flag, void* outv){
  int t = threadIdx.x, rgp = blockIdx.x;      // 1024 blocks, 128 rows each
  int lane = t & 63, w = t >> 6, l15 = lane & 15, q4 = lane >> 4;
  __shared__ __align__(16) u16 XL[16*128*32];  // 131,072 B, fragment-linear residual
  __shared__ float pscr[3072];                 // 12,288 B (8 waves x 384)
  __shared__ float totrow[384];                //  1,536 B
  if (t < 384){
    int o = t - (t/3)*3;
    totrow[t] = bs2f(canon[C_OUTB + o]) + bs2f(canon[C_OUTB + 3 + o]) + bs2f(canon[C_OUTB + 6 + o]);
  }
  // A fragment bases (two consecutive 64-row fragment-linear modB groups)
  const u16* ag0 = modB + (size_t)(rgp*2    )*32768 + q4*128 + l15*8;
  const u16* ag1 = modB + (size_t)(rgp*2 + 1)*32768 + q4*128 + l15*8;
  const u16* hl0 = hlB;
  const u16* hl1 = hlB + (size_t)HWQ*512;
  const u16* hl2 = hlB + (size_t)2*HWQ*512;
  int qbase = rgp*16;   // 128 rows = 16 q-groups
  f32x4 acc[8][4];
  __syncthreads();

  // ---- g1: X1 = relu(mod@W0 + b0 + hl0) -> XL (bf16) ; proj0 (f32) ----
  GEMMG(WT + MODT_OFF);
  {
    float ow[4][3], bias[4];
    for (int nt = 0; nt < 4; nt++){
      int c = w*64 + nt*16 + l15;
      bias[nt] = bs2f(canon[C_MODB + c]);
      for (int o = 0; o < 3; o++) ow[nt][o] = bs2f(canon[C_OUTW + c*3 + o]);
    }
    for (int mt = 0; mt < 8; mt++) for (int rg = 0; rg < 4; rg++){
      int row = mt*16 + q4*4 + rg;
      int q = qbase + (row >> 3);
      float p0 = 0.f, p1 = 0.f, p2 = 0.f;
      for (int nt = 0; nt < 4; nt++){
        int c = w*64 + nt*16 + l15;
        float v = acc[mt][nt][rg] + bias[nt] + bs2f(hl0[(size_t)q*512 + c]);
        v = fmaxf(v, 0.f);
        XL[XLI(row, c)] = f2bs(v);
        p0 += v*ow[nt][0]; p1 += v*ow[nt][1]; p2 += v*ow[nt][2];
      }
      for (int m = 1; m < 16; m <<= 1){
        p0 += __shfl_xor(p0, m, 64); p1 += __shfl_xor(p1, m, 64); p2 += __shfl_xor(p2, m, 64);
      }
      if (l15 == 0){
        pscr[w*384 + row*3 + 0] = p0;
        pscr[w*384 + row*3 + 1] = p1;
        pscr[w*384 + row*3 + 2] = p2;
      }
    }
  }
  PROJ_REDUCE;

  // ---- g2: X2 = relu(mod@W1 + b1 + hl1) + X1 -> XL (same-thread RMW) ----
  GEMMG(WT + MODT_OFF + 262144);
  {
    float bias[4];
    for (int nt = 0; nt < 4; nt++) bias[nt] = bs2f(canon[C_MODB + 512 + w*64 + nt*16 + l15]);
    for (int mt = 0; mt < 8; mt++) for (int rg = 0; rg < 4; rg++){
      int row = mt*16 + q4*4 + rg;
      int q = qbase + (row >> 3);
      for (int nt = 0; nt < 4; nt++){
        int c = w*64 + nt*16 + l15;
        float v = acc[mt][nt][rg] + bias[nt] + bs2f(hl1[(size_t)q*512 + c]);
        v = fmaxf(v, 0.f) + bs2f(XL[XLI(row, c)]);
        XL[XLI(row, c)] = f2bs(v);
      }
    }
  }
  __syncthreads();   // X2 complete before any wave's GEMML reads

  // ---- g3: X3 = relu(X2@hv0 + hvb0) ; proj1 ; X3 -> XL ----
  GEMML(WT + HVT_OFF);
  __syncthreads();   // all waves done reading X2 before overwrite
  {
    float ow[4][3], bias[4];
    for (int nt = 0; nt < 4; nt++){
      int c = w*64 + nt*16 + l15;
      bias[nt] = bs2f(canon[C_HVB + c]);
      for (int o = 0; o < 3; o++) ow[nt][o] = bs2f(canon[C_OUTW + 1536 + c*3 + o]);
    }
    for (int mt = 0; mt < 8; mt++) for (int rg = 0; rg < 4; rg++){
      int row = mt*16 + q4*4 + rg;
      float p0 = 0.f, p1 = 0.f, p2 = 0.f;
      for (int nt = 0; nt < 4; nt++){
        int c = w*64 + nt*16 + l15;
        float v = fmaxf(acc[mt][nt][rg] + bias[nt], 0.f);
        XL[XLI(row, c)] = f2bs(v);
        p0 += v*ow[nt][0]; p1 += v*ow[nt][1]; p2 += v*ow[nt][2];
      }
      for (int m = 1; m < 16; m <<= 1){
        p0 += __shfl_xor(p0, m, 64); p1 += __shfl_xor(p1, m, 64); p2 += __shfl_xor(p2, m, 64);
      }
      if (l15 == 0){
        pscr[w*384 + row*3 + 0] = p0;
        pscr[w*384 + row*3 + 1] = p1;
        pscr[w*384 + row*3 + 2] = p2;
      }
    }
  }
  PROJ_REDUCE;

  // ---- g4: X4 = relu(mod@W2 + b2 + hl2) + X3 -> XL (same-thread RMW) ----
  GEMMG(WT + MODT_OFF + 524288);
  {
    float bias[4];
    for (int nt = 0; nt < 4; nt++) bias[nt] = bs2f(canon[C_MODB + 1024 + w*64 + nt*16 + l15]);
    for (int mt = 0; mt < 8; mt++) for (int rg = 0; rg < 4; rg++){
      int row = mt*16 + q4*4 + rg;
      int q = qbase + (row >> 3);
      for (int nt = 0; nt < 4; nt++){
        int c = w*64 + nt*16 + l15;
        float v = acc[mt][nt][rg] + bias[nt] + bs2f(hl2[(size_t)q*512 + c]);
        v = fmaxf(v, 0.f) + bs2f(XL[XLI(row, c)]);
        XL[XLI(row, c)] = f2bs(v);
      }
    }
  }
  __syncthreads();   // X4 complete before any wave's GEMML reads

  // ---- g5: X5 = relu(X4@hv1 + hvb1) ; proj2 ----
  GEMML(WT + HVT_OFF + 262144);
  {
    float ow[4][3], bias[4];
    for (int nt = 0; nt < 4; nt++){
      int c = w*64 + nt*16 + l15;
      bias[nt] = bs2f(canon[C_HVB + 512 + c]);
      for (int o = 0; o < 3; o++) ow[nt][o] = bs2f(canon[C_OUTW + 3072 + c*3 + o]);
    }
    for (int mt = 0; mt < 8; mt++) for (int rg = 0; rg < 4; rg++){
      int row = mt*16 + q4*4 + rg;
      float p0 = 0.f, p1 = 0.f, p2 = 0.f;
      for (int nt = 0; nt < 4; nt++){
        float v = fmaxf(acc[mt][nt][rg] + bias[nt], 0.f);
        p0 += v*ow[nt][0]; p1 += v*ow[nt][1]; p2 += v*ow[nt][2];
      }
      for (int m = 1; m < 16; m <<= 1){
        p0 += __shfl_xor(p0, m, 64); p1 += __shfl_xor(p1, m, 64); p2 += __shfl_xor(p2, m, 64);
      }
      if (l15 == 0){
        pscr[w*384 + row*3 + 0] = p0;
        pscr[w*384 + row*3 + 1] = p1;
        pscr[w*384 + row*3 + 2] = p2;
      }
    }
  }
  PROJ_REDUCE;

  // ---- final store ----
  if (t < 384){
    int row = t / 3, o = t - (t/3)*3;
    int gr = rgp*128 + row;
    int b = gr & 7, q = gr >> 3;
    size_t idx = ((size_t)b*HWQ + q)*3 + o;
    if (*flag) ((float*)outv)[idx] = totrow[t];
    else       ((u16*)outv)[idx]   = f2bs(totrow[t]);
  }
}

extern "C" void kernel_launch(void* const* d_in, const int* in_sizes, int n_in,
                              void* d_out, int out_size, void* d_ws, size_t ws_size,
                              hipStream_t stream){
  (void)in_sizes; (void)n_in; (void)out_size;

  u16* wsp   = (u16*)d_ws;
  unsigned* flag = (unsigned*)wsp;
  u16* canon = wsp + 8;
  u16* WT    = canon + CANON_PAD;
  u16* kpart = WT + 1703936;
  u16* vT    = kpart + 262144;
  u16* qvecB = vT + 262144;
  u16* hlB   = qvecB + 2097152;
  u16* modB  = hlB + 25165824;
  if (ws_size < 199773250ULL) return;

  SrcPtrs sp;
  for (int i = 0; i < 16; i++) sp.p[i] = d_in[i];
  const float* xraw = (const float*)d_in[0];

  k_detect <<<1, 256, 0, stream>>>((const u16*)d_in[3], flag);
  k_convert<<<(C_TOTAL + 255)/256, 256, 0, stream>>>(sp, flag, canon);
  k_tr     <<<1664, 256, 0, stream>>>(canon, WT);
  k_kv     <<<2048, 256, 0, stream>>>(canon, kpart, vT);
  k_query  <<<1024, 256, 0, stream>>>(canon, xraw, flag, WT, qvecB, hlB);
  k_attn   <<<4096, 256, 0, stream>>>(canon, xraw, flag, qvecB, kpart, vT, WT, modB);
  k_bands3 <<<1024, 512, 0, stream>>>(canon, modB, WT, hlB, flag, d_out);
}

// Round 15
// 911.211 us; speedup vs baseline: 1.5347x; 1.5347x over previous
//
#include <hip/hip_runtime.h>
#include <math.h>

typedef unsigned short u16;
typedef unsigned int uint;
typedef __bf16 bf16x8 __attribute__((ext_vector_type(8)));
typedef unsigned short u16x8 __attribute__((ext_vector_type(8)));
typedef float f32x4 __attribute__((ext_vector_type(4)));

#define HWQ 16384
#define PI_F 3.14159265358979323846f

// canonical (bf16) input offsets inside ws
#define C_X     0
#define C_TOK   262144
#define C_QW    1310720
#define C_QB    1376256
#define C_WQ    1376768
#define C_WKV   1442304
#define C_WO    1704448
#define C_BO    1769984
#define C_BWW   1770496
#define C_BWB   1967104
#define C_MODW  1968640
#define C_MODB  2755072
#define C_HVW   2756608
#define C_HVB   3280896
#define C_OUTW  3281920
#define C_OUTB  3286528
#define C_TOTAL 3286537
#define CANON_PAD 3286544

// WT (transposed weights) element offsets (relative to WT base)
// QWT/WQT/WOT/BWT: [col][K] layout (used by k_query/k_attn).
// MODT/HVT: K-BLOCKED layout [kblk][col][32] (used by k_bands3).
#define QWT_OFF  0
#define WQT_OFF  65536
#define WOT_OFF  131072
#define BWT_OFF  196608
#define MODT_OFF 393216
#define HVT_OFF  1179648

struct SrcPtrs { const void* p[16]; };

__device__ __forceinline__ float bs2f(u16 u){
  unsigned v = ((unsigned)u) << 16; float f; __builtin_memcpy(&f, &v, 4); return f;
}
__device__ __forceinline__ u16 f2bs(float f){
  unsigned v; __builtin_memcpy(&v, &f, 4);
  v = (v + 0x7fffu + ((v >> 16) & 1u)) >> 16;
  return (u16)v;
}
__device__ __forceinline__ f32x4 mfma16(bf16x8 a, bf16x8 b, f32x4 c){
  return __builtin_amdgcn_mfma_f32_16x16x32_bf16(a, b, c, 0, 0, 0);
}
__device__ __forceinline__ bf16x8 ld8(const u16* p){ return *(const bf16x8*)p; }
__device__ __forceinline__ void ld2lds(const u16* g, u16* l){
  __builtin_amdgcn_global_load_lds((__attribute__((address_space(1))) const uint*)g,
                                   (__attribute__((address_space(3))) uint*)l, 16, 0, 0);
}

// ---------------- dtype detect ----------------
__global__ void k_detect(const u16* qb_raw, unsigned* flag){
  __shared__ int cnt[256];
  int t = threadIdx.x;
  u16 u = qb_raw[2*t];
  int e = (u >> 7) & 0xFF;
  cnt[t] = (e >= 126) ? 1 : 0;
  __syncthreads();
  for (int s = 128; s > 0; s >>= 1){
    if (t < s) cnt[t] += cnt[t + s];
    __syncthreads();
  }
  if (t == 0) *flag = (cnt[0] >= 16) ? 1u : 0u;
}

// ---------------- convert inputs to canonical bf16 ----------------
__global__ __launch_bounds__(256) void k_convert(SrcPtrs sp, const unsigned* flag, u16* canon){
  const int offs[17] = {C_X,C_TOK,C_QW,C_QB,C_WQ,C_WKV,C_WO,C_BO,C_BWW,C_BWB,
                        C_MODW,C_MODB,C_HVW,C_HVB,C_OUTW,C_OUTB,C_TOTAL};
  int e = blockIdx.x * 256 + threadIdx.x;
  if (e >= C_TOTAL) return;
  int seg = 0;
  for (int i = 1; i < 16; i++) if (e >= offs[i]) seg = i;
  int local = e - offs[seg];
  if (*flag) canon[e] = f2bs(((const float*)sp.p[seg])[local]);
  else       canon[e] = ((const u16*)sp.p[seg])[local];
}

// ---------------- weight transpose ----------------
// bid < 384: [col][K] layout (query/attn weights).
// bid >= 384 (mod/hv): K-BLOCKED [kblk][col][32]: elem(col,k) at (k>>5)*16384 + col*32 + (k&31).
__global__ __launch_bounds__(256) void k_tr(const u16* canon, u16* WT){
  __shared__ u16 tile[32][33];
  int bid = blockIdx.x, t = threadIdx.x;
  const u16* src; u16* dst; int K, N, tl;
  bool kblk = (bid >= 384);
  if (bid < 384){
    int m = bid >> 6; tl = bid & 63;
    if (m == 0){ src = canon + C_QW;  dst = WT + QWT_OFF; K = 128; N = 512; }
    else if (m == 1){ src = canon + C_WQ; dst = WT + WQT_OFF; K = 512; N = 128; }
    else if (m == 2){ src = canon + C_WO; dst = WT + WOT_OFF; K = 128; N = 512; }
    else { src = canon + C_BWW + (m-3)*65536; dst = WT + BWT_OFF + (m-3)*65536; K = 128; N = 512; }
  } else if (bid < 1152){
    int m = (bid - 384) >> 8; tl = (bid - 384) & 255;
    src = canon + C_MODW + m*262144; dst = WT + MODT_OFF + m*262144; K = 512; N = 512;
  } else {
    int m = (bid - 1152) >> 8; tl = (bid - 1152) & 255;
    src = canon + C_HVW + m*262144; dst = WT + HVT_OFF + m*262144; K = 512; N = 512;
  }
  int kt = K >> 5;
  int k0 = (tl % kt) * 32, n0 = (tl / kt) * 32;
  int tx = t & 31, ty = t >> 5;
  for (int r = 0; r < 4; r++)
    tile[ty + r*8][tx] = src[(size_t)(k0 + ty + r*8) * N + n0 + tx];
  __syncthreads();
  if (!kblk){
    for (int r = 0; r < 4; r++)
      dst[(size_t)(n0 + ty + r*8) * K + k0 + tx] = tile[tx][ty + r*8];
  } else {
    u16* d2 = dst + (size_t)(k0 >> 5)*16384;
    for (int r = 0; r < 4; r++)
      d2[(n0 + ty + r*8)*32 + tx] = tile[tx][ty + r*8];
  }
}

// ---------------- kv = tokens @ Wkv ----------------
__global__ __launch_bounds__(256) void k_kv(const u16* canon, u16* kpart, u16* vT){
  int b = blockIdx.x >> 8, kk = blockIdx.x & 255, t = threadIdx.x;
  const u16* tok = canon + C_TOK;
  const u16* Wkv = canon + C_WKV;
  __shared__ float tk[512];
  const u16* tr = tok + ((size_t)(b*256 + kk)) * 512;
  tk[t] = bs2f(tr[t]); tk[t+256] = bs2f(tr[t+256]);
  __syncthreads();
  float acc = 0.f;
  for (int k = 0; k < 512; k++) acc += tk[k] * bs2f(Wkv[k*256 + t]);
  if (t < 128) kpart[((size_t)(b*256 + kk))*128 + t] = f2bs(acc);
  else vT[((size_t)b*128 + (t-128))*256 + kk] = f2bs(acc);
}

// ---------------- per-query: gamma -> xq -> qvec ; h_l bands ----------------
__global__ __launch_bounds__(256) void k_query(const u16* canon, const float* xraw,
      const unsigned* flag, const u16* WT, u16* qvecB, u16* hlB){
  int t = threadIdx.x, q0 = blockIdx.x * 16;
  const u16* q_b = canon + C_QB;
  const u16* bw_b= canon + C_BWB;
  int lane = t & 63, wv = t >> 6, l15 = lane & 15, q4 = lane >> 4;
  __shared__ __align__(16) u16 g[16*136];
  __shared__ __align__(16) u16 xql[16*520];
  __shared__ float cco[32];
  __shared__ float omg[32];
  for (int e = t; e < 16*136; e += 256) g[e] = 0;
  for (int e = t; e < 16*520; e += 256) xql[e] = 0;
  if (t < 32) cco[t] = (*flag) ? xraw[q0*2 + t] : bs2f(canon[C_X + q0*2 + t]);
  if (t < 32) omg[t] = (float)pow(10.0, 1.0 + t * ((2.1072099696478683 - 1.0)/31.0));
  __syncthreads();
  for (int i = 0; i < 8; i++){
    int id = i*256 + t, qi = id >> 7, f = id & 127;
    int d = f >> 6, r = f & 63, fi = r & 31;
    float arg = PI_F * cco[qi*2 + d] * omg[fi];
    g[qi*136 + f] = f2bs((r < 32) ? sinf(arg) : cosf(arg));
  }
  __syncthreads();
  { // xq = relu(g @ q_W + q_b) -> xql
    const u16* Bm = WT + QWT_OFF;
    for (int nt = 0; nt < 8; nt++){
      f32x4 acc = {0.f,0.f,0.f,0.f};
      int c = wv*128 + nt*16 + l15;
      for (int ks = 0; ks < 4; ks++){
        bf16x8 a  = ld8(g + l15*136 + ks*32 + q4*8);
        bf16x8 bb = ld8(Bm + (size_t)c*128 + ks*32 + q4*8);
        acc = mfma16(a, bb, acc);
      }
      float qb = bs2f(q_b[c]);
      for (int rg = 0; rg < 4; rg++){
        int row = q4*4 + rg;
        xql[row*520 + c] = f2bs(fmaxf(acc[rg] + qb, 0.f));
      }
    }
  }
  __syncthreads();
  { // qvec = xq @ Wq -> stage in g -> coalesced store
    const u16* Bm = WT + WQT_OFF;
    for (int nh = 0; nh < 2; nh++){
      f32x4 acc = {0.f,0.f,0.f,0.f};
      int c = wv*32 + nh*16 + l15;
      for (int ks = 0; ks < 16; ks++){
        bf16x8 a  = ld8(xql + l15*520 + ks*32 + q4*8);
        bf16x8 bb = ld8(Bm + (size_t)c*512 + ks*32 + q4*8);
        acc = mfma16(a, bb, acc);
      }
      for (int rg = 0; rg < 4; rg++)
        g[(q4*4 + rg)*128 + c] = f2bs(acc[rg]);
    }
    __syncthreads();
    {
      int rr = t >> 4, cc = (t & 15)*8;
      *(u16x8*)(qvecB + (size_t)(q0 + rr)*128 + cc) = *(const u16x8*)(g + rr*128 + cc);
    }
  }
  const double LG[3] = {1.2041199826559248, 1.8061799739838869, 2.4082399653118496};
  for (int ib = 0; ib < 3; ib++){
    __syncthreads();
    if (t < 32) omg[t] = (float)pow(10.0, 1.0 + t * ((LG[ib] - 1.0)/31.0));
    __syncthreads();
    for (int i = 0; i < 8; i++){
      int id = i*256 + t, qi = id >> 7, f = id & 127;
      int d = f >> 6, r = f & 63, fi = r & 31;
      float arg = PI_F * cco[qi*2 + d] * omg[fi];
      g[qi*136 + f] = f2bs((r < 32) ? sinf(arg) : cosf(arg));
    }
    __syncthreads();
    const u16* Bm = WT + BWT_OFF + ib*65536;
    for (int nt = 0; nt < 8; nt++){
      f32x4 acc = {0.f,0.f,0.f,0.f};
      int c = wv*128 + nt*16 + l15;
      for (int ks = 0; ks < 4; ks++){
        bf16x8 a  = ld8(g + l15*136 + ks*32 + q4*8);
        bf16x8 bb = ld8(Bm + (size_t)c*128 + ks*32 + q4*8);
        acc = mfma16(a, bb, acc);
      }
      float bias = bs2f(bw_b[ib*512 + c]);
      for (int rg = 0; rg < 4; rg++)
        xql[(q4*4 + rg)*520 + c] = f2bs(fmaxf(acc[rg] + bias, 0.f));
    }
    __syncthreads();
    for (int it = 0; it < 4; it++){
      int rr = it*4 + (t >> 6), cc = (t & 63)*8;
      *(u16x8*)(hlB + ((size_t)ib*HWQ + q0 + rr)*512 + cc) = *(const u16x8*)(xql + rr*520 + cc);
    }
  }
}

// ---------------- attention + mod projection (f32 softmax, staged store) ----------------
// modB is stored FRAGMENT-LINEAR per 64-row group:
//   row gr=(q*8+b): rgp=q>>3, r=(q&7)*8+b; elem c:
//   off = rgp*32768 + (c>>5)*2048 + (r>>4)*512 + ((c>>3)&3)*128 + (r&15)*8 + (c&7)
__global__ __launch_bounds__(256) void k_attn(const u16* canon, const float* xraw,
      const unsigned* flag, const u16* qvecB, const u16* kpart, const u16* vT,
      const u16* WT, u16* modB){
  int t = threadIdx.x;
  int b = blockIdx.x & 7, qt = blockIdx.x >> 3, q0 = qt*32;
  const u16* bo = canon + C_BO;
  int lane = t & 63, wv = t >> 6, l15 = lane & 15, q4 = lane >> 4;
  __shared__ __align__(16) u16 ql[32*136];
  __shared__ __align__(16) u16 pl[32*264];
  __shared__ __align__(16) float pf[32*264];
  __shared__ __align__(16) u16 ot[32*136];
  __shared__ float tqs[32];
  __shared__ float red[256];
  __shared__ float rst[32];
  for (int e = t; e < 32*136; e += 256){ ql[e] = 0; ot[e] = 0; }
  for (int e = t; e < 32*264; e += 256) pl[e] = 0;
  __syncthreads();
  for (int i = 0; i < 16; i++){
    int id = i*256 + t, qi = id >> 7, c = id & 127;
    ql[qi*136 + c] = qvecB[(size_t)(q0 + qi)*128 + c];
  }
  if (t < 32){
    float c0, c1;
    if (*flag){ c0 = xraw[(q0+t)*2]; c1 = xraw[(q0+t)*2 + 1]; }
    else { c0 = bs2f(canon[C_X + (q0+t)*2]); c1 = bs2f(canon[C_X + (q0+t)*2 + 1]); }
    int rr = (int)(c0*16.f), cc = (int)(c1*16.f);
    tqs[t] = (float)(rr*16 + cc) * (1.f/256.f);
  }
  __syncthreads();
  for (int h = 0; h < 2; h++){
    f32x4 sac[2][4];
    for (int mt = 0; mt < 2; mt++) for (int nt = 0; nt < 4; nt++) sac[mt][nt] = (f32x4){0.f,0.f,0.f,0.f};
    const u16* kb = kpart + (size_t)b*256*128 + h*64;
    for (int ks = 0; ks < 2; ks++){
      bf16x8 a0 = ld8(ql + l15*136 + h*64 + ks*32 + q4*8);
      bf16x8 a1 = ld8(ql + (16+l15)*136 + h*64 + ks*32 + q4*8);
      for (int nt = 0; nt < 4; nt++){
        int kk = wv*64 + nt*16 + l15;
        bf16x8 bb = ld8(kb + (size_t)kk*128 + ks*32 + q4*8);
        sac[0][nt] = mfma16(a0, bb, sac[0][nt]);
        sac[1][nt] = mfma16(a1, bb, sac[1][nt]);
      }
    }
    for (int mt = 0; mt < 2; mt++) for (int nt = 0; nt < 4; nt++){
      int kk = wv*64 + nt*16 + l15;
      float pos = ((float)kk + 0.5f) * (1.f/256.f);
      for (int rg = 0; rg < 4; rg++){
        int row = mt*16 + q4*4 + rg;
        float dd = tqs[row] - pos;
        pf[row*264 + kk] = sac[mt][nt][rg]*0.125f - 10.f*dd*dd;
      }
    }
    __syncthreads();
    {
      int r = t >> 3, i = t & 7;
      float* pr = pf + r*264 + i*32;
      u16* po = pl + r*264 + i*32;
      float m = -1e30f;
      for (int j = 0; j < 32; j++) m = fmaxf(m, pr[j]);
      red[t] = m;
      __syncthreads();
      if (t < 32){ float mm = red[t*8];
        for (int j = 1; j < 8; j++) mm = fmaxf(mm, red[t*8+j]);
        rst[t] = mm; }
      __syncthreads();
      float mm = rst[r], sum = 0.f;
      for (int j = 0; j < 32; j++){ float e = expf(pr[j] - mm); pr[j] = e; sum += e; }
      red[t] = sum;
      __syncthreads();
      if (t < 32){ float ss = 0.f;
        for (int j = 0; j < 8; j++) ss += red[t*8+j];
        rst[t] = 1.f/ss; }
      __syncthreads();
      float inv = rst[r];
      for (int j = 0; j < 32; j++) po[j] = f2bs(pr[j] * inv);
    }
    __syncthreads();
    f32x4 oac[2] = {(f32x4){0.f,0.f,0.f,0.f}, (f32x4){0.f,0.f,0.f,0.f}};
    const u16* vb = vT + ((size_t)b*128 + h*64)*256;
    int dl = wv*16 + l15;
    for (int ks = 0; ks < 8; ks++){
      bf16x8 a0 = ld8(pl + l15*264 + ks*32 + q4*8);
      bf16x8 a1 = ld8(pl + (16+l15)*264 + ks*32 + q4*8);
      bf16x8 bb = ld8(vb + (size_t)dl*256 + ks*32 + q4*8);
      oac[0] = mfma16(a0, bb, oac[0]);
      oac[1] = mfma16(a1, bb, oac[1]);
    }
    for (int mt = 0; mt < 2; mt++) for (int rg = 0; rg < 4; rg++){
      int row = mt*16 + q4*4 + rg;
      ot[row*136 + h*64 + dl] = f2bs(oac[mt][rg]);
    }
    __syncthreads();
  }
  u16* stg = (u16*)pf;
  const u16* wob = WT + WOT_OFF;
  for (int nt = 0; nt < 8; nt++){
    f32x4 mac[2] = {(f32x4){0.f,0.f,0.f,0.f}, (f32x4){0.f,0.f,0.f,0.f}};
    int c = wv*128 + nt*16 + l15;
    for (int ks = 0; ks < 4; ks++){
      bf16x8 a0 = ld8(ot + l15*136 + ks*32 + q4*8);
      bf16x8 a1 = ld8(ot + (16+l15)*136 + ks*32 + q4*8);
      bf16x8 bb = ld8(wob + (size_t)c*128 + ks*32 + q4*8);
      mac[0] = mfma16(a0, bb, mac[0]);
      mac[1] = mfma16(a1, bb, mac[1]);
    }
    float bv = bs2f(bo[c]);
    for (int mt = 0; mt < 2; mt++) for (int rg = 0; rg < 4; rg++){
      int row = mt*16 + q4*4 + rg;
      stg[row*512 + c] = f2bs(mac[mt][rg] + bv);
    }
  }
  __syncthreads();
  for (int it = 0; it < 8; it++){
    int rr = it*4 + (t >> 6), cc = (t & 63)*8;
    int q = q0 + rr;
    int rgp = q >> 3, r = (q & 7)*8 + b;
    size_t off = (size_t)rgp*32768 + (size_t)(cc >> 5)*2048 + (size_t)(r >> 4)*512
               + (size_t)((cc >> 3) & 3)*128 + (size_t)(r & 15)*8;
    *(u16x8*)(modB + off) = *(const u16x8*)(stg + rr*512 + cc);
  }
}

// ================= k_bands3 v13 (re-anchor): fused dual-GEMM phases =================
// Verified best (549 us). Phase A: accA=mod@W0, accB=mod@W1 (shared A);
// Phase B: accA=X2@hv0, accB=mod@W2; Phase C: g5. X1/X3 in f32 registers.
// 8 waves x 64 cols; fragment-linear A layouts; launch_bounds(512,2).
// LDS: XL 64K + AL 64K + pscr 6K + totrow 0.75K = 135.3 KB (1 block/CU).

#define ZACC2 for (int mt = 0; mt < 4; mt++) for (int nt = 0; nt < 4; nt++){ \
  accA[mt][nt] = (f32x4){0.f,0.f,0.f,0.f}; accB[mt][nt] = (f32x4){0.f,0.f,0.f,0.f}; }

// Fragment-linear index: elem(row, c) at
//   (c>>5)*2048 + (row>>4)*512 + ((c>>3)&3)*128 + (row&15)*8 + (c&7)
#define XLI(row, c) (((c) >> 5)*2048 + (((row) >> 4))*512 + ((((c) >> 3) & 3))*128 + (((row) & 15))*8 + ((c) & 7))

#define MM16(ACC, A0,A1,A2,A3, B0,B1,B2,B3)                                      \
  ACC[0][0]=mfma16(A0,B0,ACC[0][0]); ACC[0][1]=mfma16(A0,B1,ACC[0][1]);          \
  ACC[0][2]=mfma16(A0,B2,ACC[0][2]); ACC[0][3]=mfma16(A0,B3,ACC[0][3]);          \
  ACC[1][0]=mfma16(A1,B0,ACC[1][0]); ACC[1][1]=mfma16(A1,B1,ACC[1][1]);          \
  ACC[1][2]=mfma16(A1,B2,ACC[1][2]); ACC[1][3]=mfma16(A1,B3,ACC[1][3]);          \
  ACC[2][0]=mfma16(A2,B0,ACC[2][0]); ACC[2][1]=mfma16(A2,B1,ACC[2][1]);          \
  ACC[2][2]=mfma16(A2,B2,ACC[2][2]); ACC[2][3]=mfma16(A2,B3,ACC[2][3]);          \
  ACC[3][0]=mfma16(A3,B0,ACC[3][0]); ACC[3][1]=mfma16(A3,B1,ACC[3][1]);          \
  ACC[3][2]=mfma16(A3,B2,ACC[3][2]); ACC[3][3]=mfma16(A3,B3,ACC[3][3]);

// Phase A: shared A (Abuf, frag-linear), two B matrices (K-blocked global).
#define GEMM2A(Abuf, Bg0, Bg1)                                                   \
  { ZACC2                                                                        \
    const u16* b0p = (Bg0) + (size_t)(w*64 + l15)*32 + q4*8;                     \
    const u16* b1p = (Bg1) + (size_t)(w*64 + l15)*32 + q4*8;                     \
    const u16* ap  = (Abuf) + q4*128 + l15*8;                                    \
    _Pragma("unroll 1")                                                          \
    for (int ks = 0; ks < 16; ks++){                                             \
      bf16x8 u0=ld8(b0p+ks*16384), u1=ld8(b0p+ks*16384+512),                     \
             u2=ld8(b0p+ks*16384+1024), u3=ld8(b0p+ks*16384+1536);               \
      bf16x8 v0=ld8(b1p+ks*16384), v1=ld8(b1p+ks*16384+512),                     \
             v2=ld8(b1p+ks*16384+1024), v3=ld8(b1p+ks*16384+1536);               \
      bf16x8 a0=ld8(ap+ks*2048), a1=ld8(ap+ks*2048+512),                         \
             a2=ld8(ap+ks*2048+1024), a3=ld8(ap+ks*2048+1536);                   \
      MM16(accA, a0,a1,a2,a3, u0,u1,u2,u3)                                       \
      MM16(accB, a0,a1,a2,a3, v0,v1,v2,v3)                                       \
    } }

// Phase B: two independent (A,B) pairs: (Ab0,Bg0)->accA, (Ab1,Bg1)->accB.
#define GEMM2B(Ab0, Bg0, Ab1, Bg1)                                               \
  { ZACC2                                                                        \
    const u16* b0p = (Bg0) + (size_t)(w*64 + l15)*32 + q4*8;                     \
    const u16* b1p = (Bg1) + (size_t)(w*64 + l15)*32 + q4*8;                     \
    const u16* a0p = (Ab0) + q4*128 + l15*8;                                     \
    const u16* a1p = (Ab1) + q4*128 + l15*8;                                     \
    _Pragma("unroll 1")                                                          \
    for (int ks = 0; ks < 16; ks++){                                             \
      bf16x8 u0=ld8(b0p+ks*16384), u1=ld8(b0p+ks*16384+512),                     \
             u2=ld8(b0p+ks*16384+1024), u3=ld8(b0p+ks*16384+1536);               \
      bf16x8 v0=ld8(b1p+ks*16384), v1=ld8(b1p+ks*16384+512),                     \
             v2=ld8(b1p+ks*16384+1024), v3=ld8(b1p+ks*16384+1536);               \
      bf16x8 x0=ld8(a0p+ks*2048), x1=ld8(a0p+ks*2048+512),                       \
             x2=ld8(a0p+ks*2048+1024), x3=ld8(a0p+ks*2048+1536);                 \
      bf16x8 y0=ld8(a1p+ks*2048), y1=ld8(a1p+ks*2048+512),                       \
             y2=ld8(a1p+ks*2048+1024), y3=ld8(a1p+ks*2048+1536);                 \
      MM16(accA, x0,x1,x2,x3, u0,u1,u2,u3)                                       \
      MM16(accB, y0,y1,y2,y3, v0,v1,v2,v3)                                       \
    } }

// Phase C: single GEMM into accA.
#define GEMMC(Abuf, Bgl)                                                         \
  { for (int mt = 0; mt < 4; mt++) for (int nt = 0; nt < 4; nt++)                \
      accA[mt][nt] = (f32x4){0.f,0.f,0.f,0.f};                                   \
    const u16* bptr = (Bgl) + (size_t)(w*64 + l15)*32 + q4*8;                    \
    const u16* ap   = (Abuf) + q4*128 + l15*8;                                   \
    _Pragma("unroll 1")                                                          \
    for (int ks = 0; ks < 16; ks++){                                             \
      bf16x8 u0=ld8(bptr+ks*16384), u1=ld8(bptr+ks*16384+512),                   \
             u2=ld8(bptr+ks*16384+1024), u3=ld8(bptr+ks*16384+1536);             \
      bf16x8 a0=ld8(ap+ks*2048), a1=ld8(ap+ks*2048+512),                         \
             a2=ld8(ap+ks*2048+1024), a3=ld8(ap+ks*2048+1536);                   \
      MM16(accA, a0,a1,a2,a3, u0,u1,u2,u3)                                       \
    } }

#define PROJ_REDUCE                                                              \
  __syncthreads();                                                               \
  if (t < 192){ float s = 0.f;                                                   \
    for (int w2 = 0; w2 < 8; w2++) s += pscr[w2*192 + t];                        \
    totrow[t] += s; }                                                            \
  __syncthreads();

__global__ __launch_bounds__(512, 2) void k_bands3(const u16* canon, const u16* modB,
      const u16* WT, const u16* hlB, const unsigned* flag, void* outv){
  int t = threadIdx.x, rgp = blockIdx.x;
  int lane = t & 63, w = t >> 6, l15 = lane & 15, q4 = lane >> 4;
  __shared__ __align__(16) u16 XL[16*64*32];   // 65,536 B, fragment-linear (X2 then X4)
  __shared__ __align__(16) u16 AL[16*64*32];   // 65,536 B, fragment-linear mod rows
  __shared__ float pscr[1536];                 //  6,144 B (8 waves x 192)
  __shared__ float totrow[192];                //    768 B
  if (t < 192){
    int o = t - (t/3)*3;
    totrow[t] = bs2f(canon[C_OUTB + o]) + bs2f(canon[C_OUTB + 3 + o]) + bs2f(canon[C_OUTB + 6 + o]);
  }
  { // AL <- modB slab (identical fragment-linear layout: straight linear copy)
    const u16* src = modB + (size_t)rgp*32768;
    for (int i = 0; i < 8; i++)
      ld2lds(src + i*4096 + w*512 + lane*8, AL + i*4096 + w*512);
  }
  const u16* hl0 = hlB;
  const u16* hl1 = hlB + (size_t)HWQ*512;
  const u16* hl2 = hlB + (size_t)2*HWQ*512;
  int qbase = rgp*8;   // 64 rows = 8 q-groups
  f32x4 accA[4][4], accB[4][4];
  __syncthreads();     // AL complete (vmcnt drained by barrier)

  // ---- PHASE A: accA = mod@W0, accB = mod@W1 (shared A) ----
  GEMM2A(AL, WT + MODT_OFF, WT + MODT_OFF + 262144);
  { // epilogue: X1 (f32 regs) ; X2 = relu(accB+b1+hl1)+X1 -> XL ; proj0
    float ow[4][3], b0v[4], b1v[4];
    for (int nt = 0; nt < 4; nt++){
      int c = w*64 + nt*16 + l15;
      b0v[nt] = bs2f(canon[C_MODB + c]);
      b1v[nt] = bs2f(canon[C_MODB + 512 + c]);
      for (int o = 0; o < 3; o++) ow[nt][o] = bs2f(canon[C_OUTW + c*3 + o]);
    }
    for (int mt = 0; mt < 4; mt++) for (int rg = 0; rg < 4; rg++){
      int row = mt*16 + q4*4 + rg;
      int q = qbase + (row >> 3);
      float p0 = 0.f, p1 = 0.f, p2 = 0.f;
      for (int nt = 0; nt < 4; nt++){
        int c = w*64 + nt*16 + l15;
        float v1 = accA[mt][nt][rg] + b0v[nt] + bs2f(hl0[(size_t)q*512 + c]);
        v1 = fmaxf(v1, 0.f);
        float v2 = accB[mt][nt][rg] + b1v[nt] + bs2f(hl1[(size_t)q*512 + c]);
        v2 = fmaxf(v2, 0.f) + v1;
        XL[XLI(row, c)] = f2bs(v2);
        p0 += v1*ow[nt][0]; p1 += v1*ow[nt][1]; p2 += v1*ow[nt][2];
      }
      for (int m = 1; m < 16; m <<= 1){
        p0 += __shfl_xor(p0, m, 64); p1 += __shfl_xor(p1, m, 64); p2 += __shfl_xor(p2, m, 64);
      }
      if (l15 == 0){
        pscr[w*192 + row*3 + 0] = p0;
        pscr[w*192 + row*3 + 1] = p1;
        pscr[w*192 + row*3 + 2] = p2;
      }
    }
  }
  PROJ_REDUCE;   // barriers also publish XL (X2)

  // ---- PHASE B: accA = X2@hv0, accB = mod@W2 ----
  GEMM2B(XL, WT + HVT_OFF, AL, WT + MODT_OFF + 524288);
  __syncthreads();   // all waves done reading X2 from XL before overwrite
  { // epilogue: X3 (f32 regs) ; X4 = relu(accB+b2+hl2)+X3 -> XL ; proj1
    float ow[4][3], hb[4], b2v[4];
    for (int nt = 0; nt < 4; nt++){
      int c = w*64 + nt*16 + l15;
      hb[nt]  = bs2f(canon[C_HVB + c]);
      b2v[nt] = bs2f(canon[C_MODB + 1024 + c]);
      for (int o = 0; o < 3; o++) ow[nt][o] = bs2f(canon[C_OUTW + 1536 + c*3 + o]);
    }
    for (int mt = 0; mt < 4; mt++) for (int rg = 0; rg < 4; rg++){
      int row = mt*16 + q4*4 + rg;
      int q = qbase + (row >> 3);
      float p0 = 0.f, p1 = 0.f, p2 = 0.f;
      for (int nt = 0; nt < 4; nt++){
        int c = w*64 + nt*16 + l15;
        float v3 = fmaxf(accA[mt][nt][rg] + hb[nt], 0.f);
        float v4 = accB[mt][nt][rg] + b2v[nt] + bs2f(hl2[(size_t)q*512 + c]);
        v4 = fmaxf(v4, 0.f) + v3;
        XL[XLI(row, c)] = f2bs(v4);
        p0 += v3*ow[nt][0]; p1 += v3*ow[nt][1]; p2 += v3*ow[nt][2];
      }
      for (int m = 1; m < 16; m <<= 1){
        p0 += __shfl_xor(p0, m, 64); p1 += __shfl_xor(p1, m, 64); p2 += __shfl_xor(p2, m, 64);
      }
      if (l15 == 0){
        pscr[w*192 + row*3 + 0] = p0;
        pscr[w*192 + row*3 + 1] = p1;
        pscr[w*192 + row*3 + 2] = p2;
      }
    }
  }
  PROJ_REDUCE;   // barriers also publish XL (X4)

  // ---- PHASE C: g5 = X4@hv1 ; proj2 ----
  GEMMC(XL, WT + HVT_OFF + 262144);
  {
    float ow[4][3], hb[4];
    for (int nt = 0; nt < 4; nt++){
      int c = w*64 + nt*16 + l15;
      hb[nt] = bs2f(canon[C_HVB + 512 + c]);
      for (int o = 0; o < 3; o++) ow[nt][o] = bs2f(canon[C_OUTW + 3072 + c*3 + o]);
    }
    for (int mt = 0; mt < 4; mt++) for (int rg = 0; rg < 4; rg++){
      int row = mt*16 + q4*4 + rg;
      float p0 = 0.f, p1 = 0.f, p2 = 0.f;
      for (int nt = 0; nt < 4; nt++){
        float v = fmaxf(accA[mt][nt][rg] + hb[nt], 0.f);
        p0 += v*ow[nt][0]; p1 += v*ow[nt][1]; p2 += v*ow[nt][2];
      }
      for (int m = 1; m < 16; m <<= 1){
        p0 += __shfl_xor(p0, m, 64); p1 += __shfl_xor(p1, m, 64); p2 += __shfl_xor(p2, m, 64);
      }
      if (l15 == 0){
        pscr[w*192 + row*3 + 0] = p0;
        pscr[w*192 + row*3 + 1] = p1;
        pscr[w*192 + row*3 + 2] = p2;
      }
    }
  }
  PROJ_REDUCE;

  // ---- final store ----
  if (t < 192){
    int row = t / 3, o = t - (t/3)*3;
    int gr = rgp*64 + row;
    int b = gr & 7, q = gr >> 3;
    size_t idx = ((size_t)b*HWQ + q)*3 + o;
    if (*flag) ((float*)outv)[idx] = totrow[t];
    else       ((u16*)outv)[idx]   = f2bs(totrow[t]);
  }
}

extern "C" void kernel_launch(void* const* d_in, const int* in_sizes, int n_in,
                              void* d_out, int out_size, void* d_ws, size_t ws_size,
                              hipStream_t stream){
  (void)in_sizes; (void)n_in; (void)out_size;

  u16* wsp   = (u16*)d_ws;
  unsigned* flag = (unsigned*)wsp;
  u16* canon = wsp + 8;
  u16* WT    = canon + CANON_PAD;
  u16* kpart = WT + 1703936;
  u16* vT    = kpart + 262144;
  u16* qvecB = vT + 262144;
  u16* hlB   = qvecB + 2097152;
  u16* modB  = hlB + 25165824;
  if (ws_size < 199773250ULL) return;

  SrcPtrs sp;
  for (int i = 0; i < 16; i++) sp.p[i] = d_in[i];
  const float* xraw = (const float*)d_in[0];

  k_detect <<<1, 256, 0, stream>>>((const u16*)d_in[3], flag);
  k_convert<<<(C_TOTAL + 255)/256, 256, 0, stream>>>(sp, flag, canon);
  k_tr     <<<1664, 256, 0, stream>>>(canon, WT);
  k_kv     <<<2048, 256, 0, stream>>>(canon, kpart, vT);
  k_query  <<<1024, 256, 0, stream>>>(canon, xraw, flag, WT, qvecB, hlB);
  k_attn   <<<4096, 256, 0, stream>>>(canon, xraw, flag, qvecB, kpart, vT, WT, modB);
  k_bands3 <<<2048, 512, 0, stream>>>(canon, modB, WT, hlB, flag, d_out);
}

// Round 16
// 868.862 us; speedup vs baseline: 1.6096x; 1.0487x over previous
//
#include <hip/hip_runtime.h>
#include <math.h>

typedef unsigned short u16;
typedef unsigned int uint;
typedef __bf16 bf16x8 __attribute__((ext_vector_type(8)));
typedef unsigned short u16x8 __attribute__((ext_vector_type(8)));
typedef float f32x4 __attribute__((ext_vector_type(4)));

#define HWQ 16384
#define PI_F 3.14159265358979323846f

// canonical (bf16) input offsets inside ws
#define C_X     0
#define C_TOK   262144
#define C_QW    1310720
#define C_QB    1376256
#define C_WQ    1376768
#define C_WKV   1442304
#define C_WO    1704448
#define C_BO    1769984
#define C_BWW   1770496
#define C_BWB   1967104
#define C_MODW  1968640
#define C_MODB  2755072
#define C_HVW   2756608
#define C_HVB   3280896
#define C_OUTW  3281920
#define C_OUTB  3286528
#define C_TOTAL 3286537
#define CANON_PAD 3286544

// WT (transposed weights) element offsets (relative to WT base)
// QWT/WQT/WOT/BWT: [col][K] layout (used by k_query/k_attn).
// MODT/HVT: K-BLOCKED layout [kblk][col][32] (used by k_bands3).
#define QWT_OFF  0
#define WQT_OFF  65536
#define WOT_OFF  131072
#define BWT_OFF  196608
#define MODT_OFF 393216
#define HVT_OFF  1179648

struct SrcPtrs { const void* p[16]; };

__device__ __forceinline__ float bs2f(u16 u){
  unsigned v = ((unsigned)u) << 16; float f; __builtin_memcpy(&f, &v, 4); return f;
}
__device__ __forceinline__ u16 f2bs(float f){
  unsigned v; __builtin_memcpy(&v, &f, 4);
  v = (v + 0x7fffu + ((v >> 16) & 1u)) >> 16;
  return (u16)v;
}
__device__ __forceinline__ f32x4 mfma16(bf16x8 a, bf16x8 b, f32x4 c){
  return __builtin_amdgcn_mfma_f32_16x16x32_bf16(a, b, c, 0, 0, 0);
}
__device__ __forceinline__ bf16x8 ld8(const u16* p){ return *(const bf16x8*)p; }
__device__ __forceinline__ void ld2lds(const u16* g, u16* l){
  __builtin_amdgcn_global_load_lds((__attribute__((address_space(1))) const uint*)g,
                                   (__attribute__((address_space(3))) uint*)l, 16, 0, 0);
}

// ---------------- dtype detect ----------------
__global__ void k_detect(const u16* qb_raw, unsigned* flag){
  __shared__ int cnt[256];
  int t = threadIdx.x;
  u16 u = qb_raw[2*t];
  int e = (u >> 7) & 0xFF;
  cnt[t] = (e >= 126) ? 1 : 0;
  __syncthreads();
  for (int s = 128; s > 0; s >>= 1){
    if (t < s) cnt[t] += cnt[t + s];
    __syncthreads();
  }
  if (t == 0) *flag = (cnt[0] >= 16) ? 1u : 0u;
}

// ---------------- convert inputs to canonical bf16 ----------------
__global__ __launch_bounds__(256) void k_convert(SrcPtrs sp, const unsigned* flag, u16* canon){
  const int offs[17] = {C_X,C_TOK,C_QW,C_QB,C_WQ,C_WKV,C_WO,C_BO,C_BWW,C_BWB,
                        C_MODW,C_MODB,C_HVW,C_HVB,C_OUTW,C_OUTB,C_TOTAL};
  int e = blockIdx.x * 256 + threadIdx.x;
  if (e >= C_TOTAL) return;
  int seg = 0;
  for (int i = 1; i < 16; i++) if (e >= offs[i]) seg = i;
  int local = e - offs[seg];
  if (*flag) canon[e] = f2bs(((const float*)sp.p[seg])[local]);
  else       canon[e] = ((const u16*)sp.p[seg])[local];
}

// ---------------- weight transpose ----------------
// bid < 384: [col][K] layout (query/attn weights).
// bid >= 384 (mod/hv): K-BLOCKED [kblk][col][32]: elem(col,k) at (k>>5)*16384 + col*32 + (k&31).
__global__ __launch_bounds__(256) void k_tr(const u16* canon, u16* WT){
  __shared__ u16 tile[32][33];
  int bid = blockIdx.x, t = threadIdx.x;
  const u16* src; u16* dst; int K, N, tl;
  bool kblk = (bid >= 384);
  if (bid < 384){
    int m = bid >> 6; tl = bid & 63;
    if (m == 0){ src = canon + C_QW;  dst = WT + QWT_OFF; K = 128; N = 512; }
    else if (m == 1){ src = canon + C_WQ; dst = WT + WQT_OFF; K = 512; N = 128; }
    else if (m == 2){ src = canon + C_WO; dst = WT + WOT_OFF; K = 128; N = 512; }
    else { src = canon + C_BWW + (m-3)*65536; dst = WT + BWT_OFF + (m-3)*65536; K = 128; N = 512; }
  } else if (bid < 1152){
    int m = (bid - 384) >> 8; tl = (bid - 384) & 255;
    src = canon + C_MODW + m*262144; dst = WT + MODT_OFF + m*262144; K = 512; N = 512;
  } else {
    int m = (bid - 1152) >> 8; tl = (bid - 1152) & 255;
    src = canon + C_HVW + m*262144; dst = WT + HVT_OFF + m*262144; K = 512; N = 512;
  }
  int kt = K >> 5;
  int k0 = (tl % kt) * 32, n0 = (tl / kt) * 32;
  int tx = t & 31, ty = t >> 5;
  for (int r = 0; r < 4; r++)
    tile[ty + r*8][tx] = src[(size_t)(k0 + ty + r*8) * N + n0 + tx];
  __syncthreads();
  if (!kblk){
    for (int r = 0; r < 4; r++)
      dst[(size_t)(n0 + ty + r*8) * K + k0 + tx] = tile[tx][ty + r*8];
  } else {
    u16* d2 = dst + (size_t)(k0 >> 5)*16384;
    for (int r = 0; r < 4; r++)
      d2[(n0 + ty + r*8)*32 + tx] = tile[tx][ty + r*8];
  }
}

// ---------------- kv = tokens @ Wkv ----------------
__global__ __launch_bounds__(256) void k_kv(const u16* canon, u16* kpart, u16* vT){
  int b = blockIdx.x >> 8, kk = blockIdx.x & 255, t = threadIdx.x;
  const u16* tok = canon + C_TOK;
  const u16* Wkv = canon + C_WKV;
  __shared__ float tk[512];
  const u16* tr = tok + ((size_t)(b*256 + kk)) * 512;
  tk[t] = bs2f(tr[t]); tk[t+256] = bs2f(tr[t+256]);
  __syncthreads();
  float acc = 0.f;
  for (int k = 0; k < 512; k++) acc += tk[k] * bs2f(Wkv[k*256 + t]);
  if (t < 128) kpart[((size_t)(b*256 + kk))*128 + t] = f2bs(acc);
  else vT[((size_t)b*128 + (t-128))*256 + kk] = f2bs(acc);
}

// ---------------- per-query: gamma -> xq -> qvec ; h_l bands ----------------
__global__ __launch_bounds__(256) void k_query(const u16* canon, const float* xraw,
      const unsigned* flag, const u16* WT, u16* qvecB, u16* hlB){
  int t = threadIdx.x, q0 = blockIdx.x * 16;
  const u16* q_b = canon + C_QB;
  const u16* bw_b= canon + C_BWB;
  int lane = t & 63, wv = t >> 6, l15 = lane & 15, q4 = lane >> 4;
  __shared__ __align__(16) u16 g[16*136];
  __shared__ __align__(16) u16 xql[16*520];
  __shared__ float cco[32];
  __shared__ float omg[32];
  for (int e = t; e < 16*136; e += 256) g[e] = 0;
  for (int e = t; e < 16*520; e += 256) xql[e] = 0;
  if (t < 32) cco[t] = (*flag) ? xraw[q0*2 + t] : bs2f(canon[C_X + q0*2 + t]);
  if (t < 32) omg[t] = (float)pow(10.0, 1.0 + t * ((2.1072099696478683 - 1.0)/31.0));
  __syncthreads();
  for (int i = 0; i < 8; i++){
    int id = i*256 + t, qi = id >> 7, f = id & 127;
    int d = f >> 6, r = f & 63, fi = r & 31;
    float arg = PI_F * cco[qi*2 + d] * omg[fi];
    g[qi*136 + f] = f2bs((r < 32) ? sinf(arg) : cosf(arg));
  }
  __syncthreads();
  { // xq = relu(g @ q_W + q_b) -> xql
    const u16* Bm = WT + QWT_OFF;
    for (int nt = 0; nt < 8; nt++){
      f32x4 acc = {0.f,0.f,0.f,0.f};
      int c = wv*128 + nt*16 + l15;
      for (int ks = 0; ks < 4; ks++){
        bf16x8 a  = ld8(g + l15*136 + ks*32 + q4*8);
        bf16x8 bb = ld8(Bm + (size_t)c*128 + ks*32 + q4*8);
        acc = mfma16(a, bb, acc);
      }
      float qb = bs2f(q_b[c]);
      for (int rg = 0; rg < 4; rg++){
        int row = q4*4 + rg;
        xql[row*520 + c] = f2bs(fmaxf(acc[rg] + qb, 0.f));
      }
    }
  }
  __syncthreads();
  { // qvec = xq @ Wq -> stage in g -> coalesced store
    const u16* Bm = WT + WQT_OFF;
    for (int nh = 0; nh < 2; nh++){
      f32x4 acc = {0.f,0.f,0.f,0.f};
      int c = wv*32 + nh*16 + l15;
      for (int ks = 0; ks < 16; ks++){
        bf16x8 a  = ld8(xql + l15*520 + ks*32 + q4*8);
        bf16x8 bb = ld8(Bm + (size_t)c*512 + ks*32 + q4*8);
        acc = mfma16(a, bb, acc);
      }
      for (int rg = 0; rg < 4; rg++)
        g[(q4*4 + rg)*128 + c] = f2bs(acc[rg]);
    }
    __syncthreads();
    {
      int rr = t >> 4, cc = (t & 15)*8;
      *(u16x8*)(qvecB + (size_t)(q0 + rr)*128 + cc) = *(const u16x8*)(g + rr*128 + cc);
    }
  }
  const double LG[3] = {1.2041199826559248, 1.8061799739838869, 2.4082399653118496};
  for (int ib = 0; ib < 3; ib++){
    __syncthreads();
    if (t < 32) omg[t] = (float)pow(10.0, 1.0 + t * ((LG[ib] - 1.0)/31.0));
    __syncthreads();
    for (int i = 0; i < 8; i++){
      int id = i*256 + t, qi = id >> 7, f = id & 127;
      int d = f >> 6, r = f & 63, fi = r & 31;
      float arg = PI_F * cco[qi*2 + d] * omg[fi];
      g[qi*136 + f] = f2bs((r < 32) ? sinf(arg) : cosf(arg));
    }
    __syncthreads();
    const u16* Bm = WT + BWT_OFF + ib*65536;
    for (int nt = 0; nt < 8; nt++){
      f32x4 acc = {0.f,0.f,0.f,0.f};
      int c = wv*128 + nt*16 + l15;
      for (int ks = 0; ks < 4; ks++){
        bf16x8 a  = ld8(g + l15*136 + ks*32 + q4*8);
        bf16x8 bb = ld8(Bm + (size_t)c*128 + ks*32 + q4*8);
        acc = mfma16(a, bb, acc);
      }
      float bias = bs2f(bw_b[ib*512 + c]);
      for (int rg = 0; rg < 4; rg++)
        xql[(q4*4 + rg)*520 + c] = f2bs(fmaxf(acc[rg] + bias, 0.f));
    }
    __syncthreads();
    for (int it = 0; it < 4; it++){
      int rr = it*4 + (t >> 6), cc = (t & 63)*8;
      *(u16x8*)(hlB + ((size_t)ib*HWQ + q0 + rr)*512 + cc) = *(const u16x8*)(xql + rr*520 + cc);
    }
  }
}

// ---------------- attention + mod projection v2 ----------------
// Register-resident scores, shuffle+small-LDS row reductions (2 barriers/head),
// DEFERRED normalization (PV on unnormalized exp, scale output by 1/sum),
// no zero-init (pads never read), stg aliased onto pl. LDS ~51KB -> 3 blocks/CU.
// modB stored FRAGMENT-LINEAR per 64-row group (same as before).
__global__ __launch_bounds__(256) void k_attn(const u16* canon, const float* xraw,
      const unsigned* flag, const u16* qvecB, const u16* kpart, const u16* vT,
      const u16* WT, u16* modB){
  int t = threadIdx.x;
  int b = blockIdx.x & 7, qt = blockIdx.x >> 3, q0 = qt*32;
  const u16* bo = canon + C_BO;
  int lane = t & 63, wv = t >> 6, l15 = lane & 15, q4 = lane >> 4;
  __shared__ __align__(16) u16 ql[32*136];
  __shared__ __align__(16) u16 sbuf[32*512];   // pl (32x264) during heads; stg (32x512) after
  __shared__ __align__(16) u16 ot[32*136];
  __shared__ float tqs[32];
  __shared__ float rred [128];                 // per-wave row max partials (4 waves x 32 rows)
  __shared__ float rred2[128];                 // per-wave row sum partials
  for (int i = 0; i < 16; i++){
    int id = i*256 + t, qi = id >> 7, c = id & 127;
    ql[qi*136 + c] = qvecB[(size_t)(q0 + qi)*128 + c];
  }
  if (t < 32){
    float c0, c1;
    if (*flag){ c0 = xraw[(q0+t)*2]; c1 = xraw[(q0+t)*2 + 1]; }
    else { c0 = bs2f(canon[C_X + (q0+t)*2]); c1 = bs2f(canon[C_X + (q0+t)*2 + 1]); }
    int rr = (int)(c0*16.f), cc = (int)(c1*16.f);
    tqs[t] = (float)(rr*16 + cc) * (1.f/256.f);
  }
  __syncthreads();
  u16* pl = sbuf;                               // row stride 264
  for (int h = 0; h < 2; h++){
    f32x4 sac[2][4];
    for (int mt = 0; mt < 2; mt++) for (int nt = 0; nt < 4; nt++) sac[mt][nt] = (f32x4){0.f,0.f,0.f,0.f};
    const u16* kb = kpart + (size_t)b*256*128 + h*64;
    for (int ks = 0; ks < 2; ks++){
      bf16x8 a0 = ld8(ql + l15*136 + h*64 + ks*32 + q4*8);
      bf16x8 a1 = ld8(ql + (16+l15)*136 + h*64 + ks*32 + q4*8);
      for (int nt = 0; nt < 4; nt++){
        int kk = wv*64 + nt*16 + l15;
        bf16x8 bb = ld8(kb + (size_t)kk*128 + ks*32 + q4*8);
        sac[0][nt] = mfma16(a0, bb, sac[0][nt]);
        sac[1][nt] = mfma16(a1, bb, sac[1][nt]);
      }
    }
    // bias in-place + per-row partial max (registers)
    float pmax[8];
    for (int i = 0; i < 8; i++) pmax[i] = -1e30f;
    for (int mt = 0; mt < 2; mt++) for (int nt = 0; nt < 4; nt++){
      int kk = wv*64 + nt*16 + l15;
      float pos = ((float)kk + 0.5f) * (1.f/256.f);
      for (int rg = 0; rg < 4; rg++){
        int row = mt*16 + q4*4 + rg;
        float dd = tqs[row] - pos;
        float s = sac[mt][nt][rg]*0.125f - 10.f*dd*dd;
        sac[mt][nt][rg] = s;
        pmax[mt*4+rg] = fmaxf(pmax[mt*4+rg], s);
      }
    }
    for (int m = 1; m < 16; m <<= 1)
      for (int i = 0; i < 8; i++) pmax[i] = fmaxf(pmax[i], __shfl_xor(pmax[i], m, 64));
    if (l15 == 0)
      for (int i = 0; i < 8; i++){
        int row = (i>>2)*16 + q4*4 + (i&3);
        rred[wv*32 + row] = pmax[i];
      }
    __syncthreads();                            // (1) rmax published
    float gmax[8];
    for (int i = 0; i < 8; i++){
      int row = (i>>2)*16 + q4*4 + (i&3);
      gmax[i] = fmaxf(fmaxf(rred[row], rred[32+row]), fmaxf(rred[64+row], rred[96+row]));
    }
    // exp (unnormalized) -> pl ; per-row partial sum
    float psum[8];
    for (int i = 0; i < 8; i++) psum[i] = 0.f;
    for (int mt = 0; mt < 2; mt++) for (int nt = 0; nt < 4; nt++){
      int kk = wv*64 + nt*16 + l15;
      for (int rg = 0; rg < 4; rg++){
        int row = mt*16 + q4*4 + rg;
        float e = expf(sac[mt][nt][rg] - gmax[mt*4+rg]);
        pl[row*264 + kk] = f2bs(e);
        psum[mt*4+rg] += e;
      }
    }
    for (int m = 1; m < 16; m <<= 1)
      for (int i = 0; i < 8; i++) psum[i] += __shfl_xor(psum[i], m, 64);
    if (l15 == 0)
      for (int i = 0; i < 8; i++){
        int row = (i>>2)*16 + q4*4 + (i&3);
        rred2[wv*32 + row] = psum[i];
      }
    __syncthreads();                            // (2) rsum + pl published
    float inv[8];
    for (int i = 0; i < 8; i++){
      int row = (i>>2)*16 + q4*4 + (i&3);
      inv[i] = 1.f/(rred2[row] + rred2[32+row] + rred2[64+row] + rred2[96+row]);
    }
    // PV on unnormalized P; scale output by inv
    f32x4 oac[2] = {(f32x4){0.f,0.f,0.f,0.f}, (f32x4){0.f,0.f,0.f,0.f}};
    const u16* vb = vT + ((size_t)b*128 + h*64)*256;
    int dl = wv*16 + l15;
    for (int ks = 0; ks < 8; ks++){
      bf16x8 a0 = ld8(pl + l15*264 + ks*32 + q4*8);
      bf16x8 a1 = ld8(pl + (16+l15)*264 + ks*32 + q4*8);
      bf16x8 bb = ld8(vb + (size_t)dl*256 + ks*32 + q4*8);
      oac[0] = mfma16(a0, bb, oac[0]);
      oac[1] = mfma16(a1, bb, oac[1]);
    }
    for (int mt = 0; mt < 2; mt++) for (int rg = 0; rg < 4; rg++){
      int row = mt*16 + q4*4 + rg;
      ot[row*136 + h*64 + dl] = f2bs(oac[mt][rg] * inv[mt*4+rg]);
    }
  }
  __syncthreads();                              // ot complete; pl free for stg overlay
  u16* stg = sbuf;                              // row stride 512
  const u16* wob = WT + WOT_OFF;
  for (int nt = 0; nt < 8; nt++){
    f32x4 mac[2] = {(f32x4){0.f,0.f,0.f,0.f}, (f32x4){0.f,0.f,0.f,0.f}};
    int c = wv*128 + nt*16 + l15;
    for (int ks = 0; ks < 4; ks++){
      bf16x8 a0 = ld8(ot + l15*136 + ks*32 + q4*8);
      bf16x8 a1 = ld8(ot + (16+l15)*136 + ks*32 + q4*8);
      bf16x8 bb = ld8(wob + (size_t)c*128 + ks*32 + q4*8);
      mac[0] = mfma16(a0, bb, mac[0]);
      mac[1] = mfma16(a1, bb, mac[1]);
    }
    float bv = bs2f(bo[c]);
    for (int mt = 0; mt < 2; mt++) for (int rg = 0; rg < 4; rg++){
      int row = mt*16 + q4*4 + rg;
      stg[row*512 + c] = f2bs(mac[mt][rg] + bv);
    }
  }
  __syncthreads();
  for (int it = 0; it < 8; it++){
    int rr = it*4 + (t >> 6), cc = (t & 63)*8;
    int q = q0 + rr;
    int rgp = q >> 3, r = (q & 7)*8 + b;
    size_t off = (size_t)rgp*32768 + (size_t)(cc >> 5)*2048 + (size_t)(r >> 4)*512
               + (size_t)((cc >> 3) & 3)*128 + (size_t)(r & 15)*8;
    *(u16x8*)(modB + off) = *(const u16x8*)(stg + rr*512 + cc);
  }
}

// ================= k_bands3 v13 (verified best, unchanged): fused dual-GEMM phases =================
#define ZACC2 for (int mt = 0; mt < 4; mt++) for (int nt = 0; nt < 4; nt++){ \
  accA[mt][nt] = (f32x4){0.f,0.f,0.f,0.f}; accB[mt][nt] = (f32x4){0.f,0.f,0.f,0.f}; }

#define XLI(row, c) (((c) >> 5)*2048 + (((row) >> 4))*512 + ((((c) >> 3) & 3))*128 + (((row) & 15))*8 + ((c) & 7))

#define MM16(ACC, A0,A1,A2,A3, B0,B1,B2,B3)                                      \
  ACC[0][0]=mfma16(A0,B0,ACC[0][0]); ACC[0][1]=mfma16(A0,B1,ACC[0][1]);          \
  ACC[0][2]=mfma16(A0,B2,ACC[0][2]); ACC[0][3]=mfma16(A0,B3,ACC[0][3]);          \
  ACC[1][0]=mfma16(A1,B0,ACC[1][0]); ACC[1][1]=mfma16(A1,B1,ACC[1][1]);          \
  ACC[1][2]=mfma16(A1,B2,ACC[1][2]); ACC[1][3]=mfma16(A1,B3,ACC[1][3]);          \
  ACC[2][0]=mfma16(A2,B0,ACC[2][0]); ACC[2][1]=mfma16(A2,B1,ACC[2][1]);          \
  ACC[2][2]=mfma16(A2,B2,ACC[2][2]); ACC[2][3]=mfma16(A2,B3,ACC[2][3]);          \
  ACC[3][0]=mfma16(A3,B0,ACC[3][0]); ACC[3][1]=mfma16(A3,B1,ACC[3][1]);          \
  ACC[3][2]=mfma16(A3,B2,ACC[3][2]); ACC[3][3]=mfma16(A3,B3,ACC[3][3]);

#define GEMM2A(Abuf, Bg0, Bg1)                                                   \
  { ZACC2                                                                        \
    const u16* b0p = (Bg0) + (size_t)(w*64 + l15)*32 + q4*8;                     \
    const u16* b1p = (Bg1) + (size_t)(w*64 + l15)*32 + q4*8;                     \
    const u16* ap  = (Abuf) + q4*128 + l15*8;                                    \
    _Pragma("unroll 1")                                                          \
    for (int ks = 0; ks < 16; ks++){                                             \
      bf16x8 u0=ld8(b0p+ks*16384), u1=ld8(b0p+ks*16384+512),                     \
             u2=ld8(b0p+ks*16384+1024), u3=ld8(b0p+ks*16384+1536);               \
      bf16x8 v0=ld8(b1p+ks*16384), v1=ld8(b1p+ks*16384+512),                     \
             v2=ld8(b1p+ks*16384+1024), v3=ld8(b1p+ks*16384+1536);               \
      bf16x8 a0=ld8(ap+ks*2048), a1=ld8(ap+ks*2048+512),                         \
             a2=ld8(ap+ks*2048+1024), a3=ld8(ap+ks*2048+1536);                   \
      MM16(accA, a0,a1,a2,a3, u0,u1,u2,u3)                                       \
      MM16(accB, a0,a1,a2,a3, v0,v1,v2,v3)                                       \
    } }

#define GEMM2B(Ab0, Bg0, Ab1, Bg1)                                               \
  { ZACC2                                                                        \
    const u16* b0p = (Bg0) + (size_t)(w*64 + l15)*32 + q4*8;                     \
    const u16* b1p = (Bg1) + (size_t)(w*64 + l15)*32 + q4*8;                     \
    const u16* a0p = (Ab0) + q4*128 + l15*8;                                     \
    const u16* a1p = (Ab1) + q4*128 + l15*8;                                     \
    _Pragma("unroll 1")                                                          \
    for (int ks = 0; ks < 16; ks++){                                             \
      bf16x8 u0=ld8(b0p+ks*16384), u1=ld8(b0p+ks*16384+512),                     \
             u2=ld8(b0p+ks*16384+1024), u3=ld8(b0p+ks*16384+1536);               \
      bf16x8 v0=ld8(b1p+ks*16384), v1=ld8(b1p+ks*16384+512),                     \
             v2=ld8(b1p+ks*16384+1024), v3=ld8(b1p+ks*16384+1536);               \
      bf16x8 x0=ld8(a0p+ks*2048), x1=ld8(a0p+ks*2048+512),                       \
             x2=ld8(a0p+ks*2048+1024), x3=ld8(a0p+ks*2048+1536);                 \
      bf16x8 y0=ld8(a1p+ks*2048), y1=ld8(a1p+ks*2048+512),                       \
             y2=ld8(a1p+ks*2048+1024), y3=ld8(a1p+ks*2048+1536);                 \
      MM16(accA, x0,x1,x2,x3, u0,u1,u2,u3)                                       \
      MM16(accB, y0,y1,y2,y3, v0,v1,v2,v3)                                       \
    } }

#define GEMMC(Abuf, Bgl)                                                         \
  { for (int mt = 0; mt < 4; mt++) for (int nt = 0; nt < 4; nt++)                \
      accA[mt][nt] = (f32x4){0.f,0.f,0.f,0.f};                                   \
    const u16* bptr = (Bgl) + (size_t)(w*64 + l15)*32 + q4*8;                    \
    const u16* ap   = (Abuf) + q4*128 + l15*8;                                   \
    _Pragma("unroll 1")                                                          \
    for (int ks = 0; ks < 16; ks++){                                             \
      bf16x8 u0=ld8(bptr+ks*16384), u1=ld8(bptr+ks*16384+512),                   \
             u2=ld8(bptr+ks*16384+1024), u3=ld8(bptr+ks*16384+1536);             \
      bf16x8 a0=ld8(ap+ks*2048), a1=ld8(ap+ks*2048+512),                         \
             a2=ld8(ap+ks*2048+1024), a3=ld8(ap+ks*2048+1536);                   \
      MM16(accA, a0,a1,a2,a3, u0,u1,u2,u3)                                       \
    } }

#define PROJ_REDUCE                                                              \
  __syncthreads();                                                               \
  if (t < 192){ float s = 0.f;                                                   \
    for (int w2 = 0; w2 < 8; w2++) s += pscr[w2*192 + t];                        \
    totrow[t] += s; }                                                            \
  __syncthreads();

__global__ __launch_bounds__(512, 2) void k_bands3(const u16* canon, const u16* modB,
      const u16* WT, const u16* hlB, const unsigned* flag, void* outv){
  int t = threadIdx.x, rgp = blockIdx.x;
  int lane = t & 63, w = t >> 6, l15 = lane & 15, q4 = lane >> 4;
  __shared__ __align__(16) u16 XL[16*64*32];
  __shared__ __align__(16) u16 AL[16*64*32];
  __shared__ float pscr[1536];
  __shared__ float totrow[192];
  if (t < 192){
    int o = t - (t/3)*3;
    totrow[t] = bs2f(canon[C_OUTB + o]) + bs2f(canon[C_OUTB + 3 + o]) + bs2f(canon[C_OUTB + 6 + o]);
  }
  {
    const u16* src = modB + (size_t)rgp*32768;
    for (int i = 0; i < 8; i++)
      ld2lds(src + i*4096 + w*512 + lane*8, AL + i*4096 + w*512);
  }
  const u16* hl0 = hlB;
  const u16* hl1 = hlB + (size_t)HWQ*512;
  const u16* hl2 = hlB + (size_t)2*HWQ*512;
  int qbase = rgp*8;
  f32x4 accA[4][4], accB[4][4];
  __syncthreads();

  // ---- PHASE A: accA = mod@W0, accB = mod@W1 (shared A) ----
  GEMM2A(AL, WT + MODT_OFF, WT + MODT_OFF + 262144);
  {
    float ow[4][3], b0v[4], b1v[4];
    for (int nt = 0; nt < 4; nt++){
      int c = w*64 + nt*16 + l15;
      b0v[nt] = bs2f(canon[C_MODB + c]);
      b1v[nt] = bs2f(canon[C_MODB + 512 + c]);
      for (int o = 0; o < 3; o++) ow[nt][o] = bs2f(canon[C_OUTW + c*3 + o]);
    }
    for (int mt = 0; mt < 4; mt++) for (int rg = 0; rg < 4; rg++){
      int row = mt*16 + q4*4 + rg;
      int q = qbase + (row >> 3);
      float p0 = 0.f, p1 = 0.f, p2 = 0.f;
      for (int nt = 0; nt < 4; nt++){
        int c = w*64 + nt*16 + l15;
        float v1 = accA[mt][nt][rg] + b0v[nt] + bs2f(hl0[(size_t)q*512 + c]);
        v1 = fmaxf(v1, 0.f);
        float v2 = accB[mt][nt][rg] + b1v[nt] + bs2f(hl1[(size_t)q*512 + c]);
        v2 = fmaxf(v2, 0.f) + v1;
        XL[XLI(row, c)] = f2bs(v2);
        p0 += v1*ow[nt][0]; p1 += v1*ow[nt][1]; p2 += v1*ow[nt][2];
      }
      for (int m = 1; m < 16; m <<= 1){
        p0 += __shfl_xor(p0, m, 64); p1 += __shfl_xor(p1, m, 64); p2 += __shfl_xor(p2, m, 64);
      }
      if (l15 == 0){
        pscr[w*192 + row*3 + 0] = p0;
        pscr[w*192 + row*3 + 1] = p1;
        pscr[w*192 + row*3 + 2] = p2;
      }
    }
  }
  PROJ_REDUCE;

  // ---- PHASE B: accA = X2@hv0, accB = mod@W2 ----
  GEMM2B(XL, WT + HVT_OFF, AL, WT + MODT_OFF + 524288);
  __syncthreads();
  {
    float ow[4][3], hb[4], b2v[4];
    for (int nt = 0; nt < 4; nt++){
      int c = w*64 + nt*16 + l15;
      hb[nt]  = bs2f(canon[C_HVB + c]);
      b2v[nt] = bs2f(canon[C_MODB + 1024 + c]);
      for (int o = 0; o < 3; o++) ow[nt][o] = bs2f(canon[C_OUTW + 1536 + c*3 + o]);
    }
    for (int mt = 0; mt < 4; mt++) for (int rg = 0; rg < 4; rg++){
      int row = mt*16 + q4*4 + rg;
      int q = qbase + (row >> 3);
      float p0 = 0.f, p1 = 0.f, p2 = 0.f;
      for (int nt = 0; nt < 4; nt++){
        int c = w*64 + nt*16 + l15;
        float v3 = fmaxf(accA[mt][nt][rg] + hb[nt], 0.f);
        float v4 = accB[mt][nt][rg] + b2v[nt] + bs2f(hl2[(size_t)q*512 + c]);
        v4 = fmaxf(v4, 0.f) + v3;
        XL[XLI(row, c)] = f2bs(v4);
        p0 += v3*ow[nt][0]; p1 += v3*ow[nt][1]; p2 += v3*ow[nt][2];
      }
      for (int m = 1; m < 16; m <<= 1){
        p0 += __shfl_xor(p0, m, 64); p1 += __shfl_xor(p1, m, 64); p2 += __shfl_xor(p2, m, 64);
      }
      if (l15 == 0){
        pscr[w*192 + row*3 + 0] = p0;
        pscr[w*192 + row*3 + 1] = p1;
        pscr[w*192 + row*3 + 2] = p2;
      }
    }
  }
  PROJ_REDUCE;

  // ---- PHASE C: g5 = X4@hv1 ; proj2 ----
  GEMMC(XL, WT + HVT_OFF + 262144);
  {
    float ow[4][3], hb[4];
    for (int nt = 0; nt < 4; nt++){
      int c = w*64 + nt*16 + l15;
      hb[nt] = bs2f(canon[C_HVB + 512 + c]);
      for (int o = 0; o < 3; o++) ow[nt][o] = bs2f(canon[C_OUTW + 3072 + c*3 + o]);
    }
    for (int mt = 0; mt < 4; mt++) for (int rg = 0; rg < 4; rg++){
      int row = mt*16 + q4*4 + rg;
      float p0 = 0.f, p1 = 0.f, p2 = 0.f;
      for (int nt = 0; nt < 4; nt++){
        float v = fmaxf(accA[mt][nt][rg] + hb[nt], 0.f);
        p0 += v*ow[nt][0]; p1 += v*ow[nt][1]; p2 += v*ow[nt][2];
      }
      for (int m = 1; m < 16; m <<= 1){
        p0 += __shfl_xor(p0, m, 64); p1 += __shfl_xor(p1, m, 64); p2 += __shfl_xor(p2, m, 64);
      }
      if (l15 == 0){
        pscr[w*192 + row*3 + 0] = p0;
        pscr[w*192 + row*3 + 1] = p1;
        pscr[w*192 + row*3 + 2] = p2;
      }
    }
  }
  PROJ_REDUCE;

  // ---- final store ----
  if (t < 192){
    int row = t / 3, o = t - (t/3)*3;
    int gr = rgp*64 + row;
    int b = gr & 7, q = gr >> 3;
    size_t idx = ((size_t)b*HWQ + q)*3 + o;
    if (*flag) ((float*)outv)[idx] = totrow[t];
    else       ((u16*)outv)[idx]   = f2bs(totrow[t]);
  }
}

extern "C" void kernel_launch(void* const* d_in, const int* in_sizes, int n_in,
                              void* d_out, int out_size, void* d_ws, size_t ws_size,
                              hipStream_t stream){
  (void)in_sizes; (void)n_in; (void)out_size;

  u16* wsp   = (u16*)d_ws;
  unsigned* flag = (unsigned*)wsp;
  u16* canon = wsp + 8;
  u16* WT    = canon + CANON_PAD;
  u16* kpart = WT + 1703936;
  u16* vT    = kpart + 262144;
  u16* qvecB = vT + 262144;
  u16* hlB   = qvecB + 2097152;
  u16* modB  = hlB + 25165824;
  if (ws_size < 199773250ULL) return;

  SrcPtrs sp;
  for (int i = 0; i < 16; i++) sp.p[i] = d_in[i];
  const float* xraw = (const float*)d_in[0];

  k_detect <<<1, 256, 0, stream>>>((const u16*)d_in[3], flag);
  k_convert<<<(C_TOTAL + 255)/256, 256, 0, stream>>>(sp, flag, canon);
  k_tr     <<<1664, 256, 0, stream>>>(canon, WT);
  k_kv     <<<2048, 256, 0, stream>>>(canon, kpart, vT);
  k_query  <<<1024, 256, 0, stream>>>(canon, xraw, flag, WT, qvecB, hlB);
  k_attn   <<<4096, 256, 0, stream>>>(canon, xraw, flag, qvecB, kpart, vT, WT, modB);
  k_bands3 <<<2048, 512, 0, stream>>>(canon, modB, WT, hlB, flag, d_out);
}

// Round 17
// 811.817 us; speedup vs baseline: 1.7227x; 1.0703x over previous
//
#include <hip/hip_runtime.h>
#include <math.h>

typedef unsigned short u16;
typedef unsigned int uint;
typedef __bf16 bf16x8 __attribute__((ext_vector_type(8)));
typedef unsigned short u16x8 __attribute__((ext_vector_type(8)));
typedef float f32x4 __attribute__((ext_vector_type(4)));

#define HWQ 16384
#define PI_F 3.14159265358979323846f

// canonical (bf16) input offsets inside ws
#define C_X     0
#define C_TOK   262144
#define C_QW    1310720
#define C_QB    1376256
#define C_WQ    1376768
#define C_WKV   1442304
#define C_WO    1704448
#define C_BO    1769984
#define C_BWW   1770496
#define C_BWB   1967104
#define C_MODW  1968640
#define C_MODB  2755072
#define C_HVW   2756608
#define C_HVB   3280896
#define C_OUTW  3281920
#define C_OUTB  3286528
#define C_TOTAL 3286537
#define CANON_PAD 3286544

// WT (transposed weights) element offsets (relative to WT base)
// ALL regions now K-BLOCKED [kblk][col][32]: elem(col,k) at
//   (k>>5)*(N*32) + col*32 + (k&31)   (N = #cols of the region)
#define QWT_OFF  0
#define WQT_OFF  65536
#define WOT_OFF  131072
#define BWT_OFF  196608
#define MODT_OFF 393216
#define HVT_OFF  1179648

struct SrcPtrs { const void* p[16]; };

__device__ __forceinline__ float bs2f(u16 u){
  unsigned v = ((unsigned)u) << 16; float f; __builtin_memcpy(&f, &v, 4); return f;
}
__device__ __forceinline__ u16 f2bs(float f){
  unsigned v; __builtin_memcpy(&v, &f, 4);
  v = (v + 0x7fffu + ((v >> 16) & 1u)) >> 16;
  return (u16)v;
}
__device__ __forceinline__ f32x4 mfma16(bf16x8 a, bf16x8 b, f32x4 c){
  return __builtin_amdgcn_mfma_f32_16x16x32_bf16(a, b, c, 0, 0, 0);
}
__device__ __forceinline__ bf16x8 ld8(const u16* p){ return *(const bf16x8*)p; }
__device__ __forceinline__ void ld2lds(const u16* g, u16* l){
  __builtin_amdgcn_global_load_lds((__attribute__((address_space(1))) const uint*)g,
                                   (__attribute__((address_space(3))) uint*)l, 16, 0, 0);
}

// ---------------- dtype detect ----------------
__global__ void k_detect(const u16* qb_raw, unsigned* flag){
  __shared__ int cnt[256];
  int t = threadIdx.x;
  u16 u = qb_raw[2*t];
  int e = (u >> 7) & 0xFF;
  cnt[t] = (e >= 126) ? 1 : 0;
  __syncthreads();
  for (int s = 128; s > 0; s >>= 1){
    if (t < s) cnt[t] += cnt[t + s];
    __syncthreads();
  }
  if (t == 0) *flag = (cnt[0] >= 16) ? 1u : 0u;
}

// ---------------- convert inputs to canonical bf16 ----------------
__global__ __launch_bounds__(256) void k_convert(SrcPtrs sp, const unsigned* flag, u16* canon){
  const int offs[17] = {C_X,C_TOK,C_QW,C_QB,C_WQ,C_WKV,C_WO,C_BO,C_BWW,C_BWB,
                        C_MODW,C_MODB,C_HVW,C_HVB,C_OUTW,C_OUTB,C_TOTAL};
  int e = blockIdx.x * 256 + threadIdx.x;
  if (e >= C_TOTAL) return;
  int seg = 0;
  for (int i = 1; i < 16; i++) if (e >= offs[i]) seg = i;
  int local = e - offs[seg];
  if (*flag) canon[e] = f2bs(((const float*)sp.p[seg])[local]);
  else       canon[e] = ((const u16*)sp.p[seg])[local];
}

// ---------------- weight transpose: ALL K-blocked [kblk][col][32] ----------------
__global__ __launch_bounds__(256) void k_tr(const u16* canon, u16* WT){
  __shared__ u16 tile[32][33];
  int bid = blockIdx.x, t = threadIdx.x;
  const u16* src; u16* dst; int K, N, tl;
  if (bid < 384){
    int m = bid >> 6; tl = bid & 63;
    if (m == 0){ src = canon + C_QW;  dst = WT + QWT_OFF; K = 128; N = 512; }
    else if (m == 1){ src = canon + C_WQ; dst = WT + WQT_OFF; K = 512; N = 128; }
    else if (m == 2){ src = canon + C_WO; dst = WT + WOT_OFF; K = 128; N = 512; }
    else { src = canon + C_BWW + (m-3)*65536; dst = WT + BWT_OFF + (m-3)*65536; K = 128; N = 512; }
  } else if (bid < 1152){
    int m = (bid - 384) >> 8; tl = (bid - 384) & 255;
    src = canon + C_MODW + m*262144; dst = WT + MODT_OFF + m*262144; K = 512; N = 512;
  } else {
    int m = (bid - 1152) >> 8; tl = (bid - 1152) & 255;
    src = canon + C_HVW + m*262144; dst = WT + HVT_OFF + m*262144; K = 512; N = 512;
  }
  int kt = K >> 5;
  int k0 = (tl % kt) * 32, n0 = (tl / kt) * 32;
  int tx = t & 31, ty = t >> 5;
  for (int r = 0; r < 4; r++)
    tile[ty + r*8][tx] = src[(size_t)(k0 + ty + r*8) * N + n0 + tx];
  __syncthreads();
  u16* d2 = dst + (size_t)(k0 >> 5)*((size_t)N*32);
  for (int r = 0; r < 4; r++)
    d2[(n0 + ty + r*8)*32 + tx] = tile[tx][ty + r*8];
}

// ---------------- kv = tokens @ Wkv ----------------
// kpart K-blocked over d (head dim): per b, elem(kk,d) at (d>>5)*8192 + kk*32 + (d&31)
// vT    K-blocked over kk (key idx): per b, elem(d,kk) at (kk>>5)*4096 + d*32 + (kk&31)
__global__ __launch_bounds__(256) void k_kv(const u16* canon, u16* kpart, u16* vT){
  int b = blockIdx.x >> 8, kk = blockIdx.x & 255, t = threadIdx.x;
  const u16* tok = canon + C_TOK;
  const u16* Wkv = canon + C_WKV;
  __shared__ float tk[512];
  const u16* tr = tok + ((size_t)(b*256 + kk)) * 512;
  tk[t] = bs2f(tr[t]); tk[t+256] = bs2f(tr[t+256]);
  __syncthreads();
  float acc = 0.f;
  for (int k = 0; k < 512; k++) acc += tk[k] * bs2f(Wkv[k*256 + t]);
  if (t < 128)
    kpart[(size_t)b*32768 + (t>>5)*8192 + kk*32 + (t&31)] = f2bs(acc);
  else {
    int d = t - 128;
    vT[(size_t)b*32768 + (kk>>5)*4096 + d*32 + (kk&31)] = f2bs(acc);
  }
}

// ---------------- per-query: gamma -> xq -> qvec ; h_l bands ----------------
__global__ __launch_bounds__(256) void k_query(const u16* canon, const float* xraw,
      const unsigned* flag, const u16* WT, u16* qvecB, u16* hlB){
  int t = threadIdx.x, q0 = blockIdx.x * 16;
  const u16* q_b = canon + C_QB;
  const u16* bw_b= canon + C_BWB;
  int lane = t & 63, wv = t >> 6, l15 = lane & 15, q4 = lane >> 4;
  __shared__ __align__(16) u16 g[16*136];
  __shared__ __align__(16) u16 xql[16*520];
  __shared__ float cco[32];
  __shared__ float omg[32];
  for (int e = t; e < 16*136; e += 256) g[e] = 0;
  for (int e = t; e < 16*520; e += 256) xql[e] = 0;
  if (t < 32) cco[t] = (*flag) ? xraw[q0*2 + t] : bs2f(canon[C_X + q0*2 + t]);
  if (t < 32) omg[t] = (float)pow(10.0, 1.0 + t * ((2.1072099696478683 - 1.0)/31.0));
  __syncthreads();
  for (int i = 0; i < 8; i++){
    int id = i*256 + t, qi = id >> 7, f = id & 127;
    int d = f >> 6, r = f & 63, fi = r & 31;
    float arg = PI_F * cco[qi*2 + d] * omg[fi];
    g[qi*136 + f] = f2bs((r < 32) ? sinf(arg) : cosf(arg));
  }
  __syncthreads();
  { // xq = relu(g @ q_W + q_b) -> xql
    const u16* Bm = WT + QWT_OFF;
    for (int nt = 0; nt < 8; nt++){
      f32x4 acc = {0.f,0.f,0.f,0.f};
      int c = wv*128 + nt*16 + l15;
      for (int ks = 0; ks < 4; ks++){
        bf16x8 a  = ld8(g + l15*136 + ks*32 + q4*8);
        bf16x8 bb = ld8(Bm + ks*16384 + c*32 + q4*8);
        acc = mfma16(a, bb, acc);
      }
      float qb = bs2f(q_b[c]);
      for (int rg = 0; rg < 4; rg++){
        int row = q4*4 + rg;
        xql[row*520 + c] = f2bs(fmaxf(acc[rg] + qb, 0.f));
      }
    }
  }
  __syncthreads();
  { // qvec = xq @ Wq -> stage in g -> coalesced store
    const u16* Bm = WT + WQT_OFF;
    for (int nh = 0; nh < 2; nh++){
      f32x4 acc = {0.f,0.f,0.f,0.f};
      int c = wv*32 + nh*16 + l15;
      for (int ks = 0; ks < 16; ks++){
        bf16x8 a  = ld8(xql + l15*520 + ks*32 + q4*8);
        bf16x8 bb = ld8(Bm + ks*4096 + c*32 + q4*8);
        acc = mfma16(a, bb, acc);
      }
      for (int rg = 0; rg < 4; rg++)
        g[(q4*4 + rg)*128 + c] = f2bs(acc[rg]);
    }
    __syncthreads();
    {
      int rr = t >> 4, cc = (t & 15)*8;
      *(u16x8*)(qvecB + (size_t)(q0 + rr)*128 + cc) = *(const u16x8*)(g + rr*128 + cc);
    }
  }
  const double LG[3] = {1.2041199826559248, 1.8061799739838869, 2.4082399653118496};
  for (int ib = 0; ib < 3; ib++){
    __syncthreads();
    if (t < 32) omg[t] = (float)pow(10.0, 1.0 + t * ((LG[ib] - 1.0)/31.0));
    __syncthreads();
    for (int i = 0; i < 8; i++){
      int id = i*256 + t, qi = id >> 7, f = id & 127;
      int d = f >> 6, r = f & 63, fi = r & 31;
      float arg = PI_F * cco[qi*2 + d] * omg[fi];
      g[qi*136 + f] = f2bs((r < 32) ? sinf(arg) : cosf(arg));
    }
    __syncthreads();
    const u16* Bm = WT + BWT_OFF + ib*65536;
    for (int nt = 0; nt < 8; nt++){
      f32x4 acc = {0.f,0.f,0.f,0.f};
      int c = wv*128 + nt*16 + l15;
      for (int ks = 0; ks < 4; ks++){
        bf16x8 a  = ld8(g + l15*136 + ks*32 + q4*8);
        bf16x8 bb = ld8(Bm + ks*16384 + c*32 + q4*8);
        acc = mfma16(a, bb, acc);
      }
      float bias = bs2f(bw_b[ib*512 + c]);
      for (int rg = 0; rg < 4; rg++)
        xql[(q4*4 + rg)*520 + c] = f2bs(fmaxf(acc[rg] + bias, 0.f));
    }
    __syncthreads();
    for (int it = 0; it < 4; it++){
      int rr = it*4 + (t >> 6), cc = (t & 63)*8;
      *(u16x8*)(hlB + ((size_t)ib*HWQ + q0 + rr)*512 + cc) = *(const u16x8*)(xql + rr*520 + cc);
    }
  }
}

// ---------------- attention + mod projection v3 (K-blocked operands) ----------------
// Register-resident scores, 2 barriers/head, deferred normalization,
// stg aliased onto pl. K/V/WO loads now contiguous 1KB/fragment.
// modB stored FRAGMENT-LINEAR per 64-row group (unchanged).
__global__ __launch_bounds__(256) void k_attn(const u16* canon, const float* xraw,
      const unsigned* flag, const u16* qvecB, const u16* kpart, const u16* vT,
      const u16* WT, u16* modB){
  int t = threadIdx.x;
  int b = blockIdx.x & 7, qt = blockIdx.x >> 3, q0 = qt*32;
  const u16* bo = canon + C_BO;
  int lane = t & 63, wv = t >> 6, l15 = lane & 15, q4 = lane >> 4;
  __shared__ __align__(16) u16 ql[32*136];
  __shared__ __align__(16) u16 sbuf[32*512];   // pl (32x264) during heads; stg (32x512) after
  __shared__ __align__(16) u16 ot[32*136];
  __shared__ float tqs[32];
  __shared__ float rred [128];
  __shared__ float rred2[128];
  for (int i = 0; i < 16; i++){
    int id = i*256 + t, qi = id >> 7, c = id & 127;
    ql[qi*136 + c] = qvecB[(size_t)(q0 + qi)*128 + c];
  }
  if (t < 32){
    float c0, c1;
    if (*flag){ c0 = xraw[(q0+t)*2]; c1 = xraw[(q0+t)*2 + 1]; }
    else { c0 = bs2f(canon[C_X + (q0+t)*2]); c1 = bs2f(canon[C_X + (q0+t)*2 + 1]); }
    int rr = (int)(c0*16.f), cc = (int)(c1*16.f);
    tqs[t] = (float)(rr*16 + cc) * (1.f/256.f);
  }
  __syncthreads();
  u16* pl = sbuf;                               // row stride 264
  for (int h = 0; h < 2; h++){
    f32x4 sac[2][4];
    for (int mt = 0; mt < 2; mt++) for (int nt = 0; nt < 4; nt++) sac[mt][nt] = (f32x4){0.f,0.f,0.f,0.f};
    const u16* kb = kpart + (size_t)b*32768 + h*16384;   // K-blocked over d
    for (int ks = 0; ks < 2; ks++){
      bf16x8 a0 = ld8(ql + l15*136 + h*64 + ks*32 + q4*8);
      bf16x8 a1 = ld8(ql + (16+l15)*136 + h*64 + ks*32 + q4*8);
      for (int nt = 0; nt < 4; nt++){
        int kk = wv*64 + nt*16 + l15;
        bf16x8 bb = ld8(kb + ks*8192 + kk*32 + q4*8);
        sac[0][nt] = mfma16(a0, bb, sac[0][nt]);
        sac[1][nt] = mfma16(a1, bb, sac[1][nt]);
      }
    }
    float pmax[8];
    for (int i = 0; i < 8; i++) pmax[i] = -1e30f;
    for (int mt = 0; mt < 2; mt++) for (int nt = 0; nt < 4; nt++){
      int kk = wv*64 + nt*16 + l15;
      float pos = ((float)kk + 0.5f) * (1.f/256.f);
      for (int rg = 0; rg < 4; rg++){
        int row = mt*16 + q4*4 + rg;
        float dd = tqs[row] - pos;
        float s = sac[mt][nt][rg]*0.125f - 10.f*dd*dd;
        sac[mt][nt][rg] = s;
        pmax[mt*4+rg] = fmaxf(pmax[mt*4+rg], s);
      }
    }
    for (int m = 1; m < 16; m <<= 1)
      for (int i = 0; i < 8; i++) pmax[i] = fmaxf(pmax[i], __shfl_xor(pmax[i], m, 64));
    if (l15 == 0)
      for (int i = 0; i < 8; i++){
        int row = (i>>2)*16 + q4*4 + (i&3);
        rred[wv*32 + row] = pmax[i];
      }
    __syncthreads();
    float gmax[8];
    for (int i = 0; i < 8; i++){
      int row = (i>>2)*16 + q4*4 + (i&3);
      gmax[i] = fmaxf(fmaxf(rred[row], rred[32+row]), fmaxf(rred[64+row], rred[96+row]));
    }
    float psum[8];
    for (int i = 0; i < 8; i++) psum[i] = 0.f;
    for (int mt = 0; mt < 2; mt++) for (int nt = 0; nt < 4; nt++){
      int kk = wv*64 + nt*16 + l15;
      for (int rg = 0; rg < 4; rg++){
        int row = mt*16 + q4*4 + rg;
        float e = expf(sac[mt][nt][rg] - gmax[mt*4+rg]);
        pl[row*264 + kk] = f2bs(e);
        psum[mt*4+rg] += e;
      }
    }
    for (int m = 1; m < 16; m <<= 1)
      for (int i = 0; i < 8; i++) psum[i] += __shfl_xor(psum[i], m, 64);
    if (l15 == 0)
      for (int i = 0; i < 8; i++){
        int row = (i>>2)*16 + q4*4 + (i&3);
        rred2[wv*32 + row] = psum[i];
      }
    __syncthreads();
    float inv[8];
    for (int i = 0; i < 8; i++){
      int row = (i>>2)*16 + q4*4 + (i&3);
      inv[i] = 1.f/(rred2[row] + rred2[32+row] + rred2[64+row] + rred2[96+row]);
    }
    f32x4 oac[2] = {(f32x4){0.f,0.f,0.f,0.f}, (f32x4){0.f,0.f,0.f,0.f}};
    const u16* vb = vT + (size_t)b*32768 + h*2048;   // K-blocked over kk
    int dl = wv*16 + l15;
    for (int ks = 0; ks < 8; ks++){
      bf16x8 a0 = ld8(pl + l15*264 + ks*32 + q4*8);
      bf16x8 a1 = ld8(pl + (16+l15)*264 + ks*32 + q4*8);
      bf16x8 bb = ld8(vb + ks*4096 + dl*32 + q4*8);
      oac[0] = mfma16(a0, bb, oac[0]);
      oac[1] = mfma16(a1, bb, oac[1]);
    }
    for (int mt = 0; mt < 2; mt++) for (int rg = 0; rg < 4; rg++){
      int row = mt*16 + q4*4 + rg;
      ot[row*136 + h*64 + dl] = f2bs(oac[mt][rg] * inv[mt*4+rg]);
    }
  }
  __syncthreads();
  u16* stg = sbuf;                              // row stride 512
  const u16* wob = WT + WOT_OFF;
  for (int nt = 0; nt < 8; nt++){
    f32x4 mac[2] = {(f32x4){0.f,0.f,0.f,0.f}, (f32x4){0.f,0.f,0.f,0.f}};
    int c = wv*128 + nt*16 + l15;
    for (int ks = 0; ks < 4; ks++){
      bf16x8 a0 = ld8(ot + l15*136 + ks*32 + q4*8);
      bf16x8 a1 = ld8(ot + (16+l15)*136 + ks*32 + q4*8);
      bf16x8 bb = ld8(wob + ks*16384 + c*32 + q4*8);
      mac[0] = mfma16(a0, bb, mac[0]);
      mac[1] = mfma16(a1, bb, mac[1]);
    }
    float bv = bs2f(bo[c]);
    for (int mt = 0; mt < 2; mt++) for (int rg = 0; rg < 4; rg++){
      int row = mt*16 + q4*4 + rg;
      stg[row*512 + c] = f2bs(mac[mt][rg] + bv);
    }
  }
  __syncthreads();
  for (int it = 0; it < 8; it++){
    int rr = it*4 + (t >> 6), cc = (t & 63)*8;
    int q = q0 + rr;
    int rgp = q >> 3, r = (q & 7)*8 + b;
    size_t off = (size_t)rgp*32768 + (size_t)(cc >> 5)*2048 + (size_t)(r >> 4)*512
               + (size_t)((cc >> 3) & 3)*128 + (size_t)(r & 15)*8;
    *(u16x8*)(modB + off) = *(const u16x8*)(stg + rr*512 + cc);
  }
}

// ================= k_bands3 v13 (verified best, unchanged): fused dual-GEMM phases =================
#define ZACC2 for (int mt = 0; mt < 4; mt++) for (int nt = 0; nt < 4; nt++){ \
  accA[mt][nt] = (f32x4){0.f,0.f,0.f,0.f}; accB[mt][nt] = (f32x4){0.f,0.f,0.f,0.f}; }

#define XLI(row, c) (((c) >> 5)*2048 + (((row) >> 4))*512 + ((((c) >> 3) & 3))*128 + (((row) & 15))*8 + ((c) & 7))

#define MM16(ACC, A0,A1,A2,A3, B0,B1,B2,B3)                                      \
  ACC[0][0]=mfma16(A0,B0,ACC[0][0]); ACC[0][1]=mfma16(A0,B1,ACC[0][1]);          \
  ACC[0][2]=mfma16(A0,B2,ACC[0][2]); ACC[0][3]=mfma16(A0,B3,ACC[0][3]);          \
  ACC[1][0]=mfma16(A1,B0,ACC[1][0]); ACC[1][1]=mfma16(A1,B1,ACC[1][1]);          \
  ACC[1][2]=mfma16(A1,B2,ACC[1][2]); ACC[1][3]=mfma16(A1,B3,ACC[1][3]);          \
  ACC[2][0]=mfma16(A2,B0,ACC[2][0]); ACC[2][1]=mfma16(A2,B1,ACC[2][1]);          \
  ACC[2][2]=mfma16(A2,B2,ACC[2][2]); ACC[2][3]=mfma16(A2,B3,ACC[2][3]);          \
  ACC[3][0]=mfma16(A3,B0,ACC[3][0]); ACC[3][1]=mfma16(A3,B1,ACC[3][1]);          \
  ACC[3][2]=mfma16(A3,B2,ACC[3][2]); ACC[3][3]=mfma16(A3,B3,ACC[3][3]);

#define GEMM2A(Abuf, Bg0, Bg1)                                                   \
  { ZACC2                                                                        \
    const u16* b0p = (Bg0) + (size_t)(w*64 + l15)*32 + q4*8;                     \
    const u16* b1p = (Bg1) + (size_t)(w*64 + l15)*32 + q4*8;                     \
    const u16* ap  = (Abuf) + q4*128 + l15*8;                                    \
    _Pragma("unroll 1")                                                          \
    for (int ks = 0; ks < 16; ks++){                                             \
      bf16x8 u0=ld8(b0p+ks*16384), u1=ld8(b0p+ks*16384+512),                     \
             u2=ld8(b0p+ks*16384+1024), u3=ld8(b0p+ks*16384+1536);               \
      bf16x8 v0=ld8(b1p+ks*16384), v1=ld8(b1p+ks*16384+512),                     \
             v2=ld8(b1p+ks*16384+1024), v3=ld8(b1p+ks*16384+1536);               \
      bf16x8 a0=ld8(ap+ks*2048), a1=ld8(ap+ks*2048+512),                         \
             a2=ld8(ap+ks*2048+1024), a3=ld8(ap+ks*2048+1536);                   \
      MM16(accA, a0,a1,a2,a3, u0,u1,u2,u3)                                       \
      MM16(accB, a0,a1,a2,a3, v0,v1,v2,v3)                                       \
    } }

#define GEMM2B(Ab0, Bg0, Ab1, Bg1)                                               \
  { ZACC2                                                                        \
    const u16* b0p = (Bg0) + (size_t)(w*64 + l15)*32 + q4*8;                     \
    const u16* b1p = (Bg1) + (size_t)(w*64 + l15)*32 + q4*8;                     \
    const u16* a0p = (Ab0) + q4*128 + l15*8;                                     \
    const u16* a1p = (Ab1) + q4*128 + l15*8;                                     \
    _Pragma("unroll 1")                                                          \
    for (int ks = 0; ks < 16; ks++){                                             \
      bf16x8 u0=ld8(b0p+ks*16384), u1=ld8(b0p+ks*16384+512),                     \
             u2=ld8(b0p+ks*16384+1024), u3=ld8(b0p+ks*16384+1536);               \
      bf16x8 v0=ld8(b1p+ks*16384), v1=ld8(b1p+ks*16384+512),                     \
             v2=ld8(b1p+ks*16384+1024), v3=ld8(b1p+ks*16384+1536);               \
      bf16x8 x0=ld8(a0p+ks*2048), x1=ld8(a0p+ks*2048+512),                       \
             x2=ld8(a0p+ks*2048+1024), x3=ld8(a0p+ks*2048+1536);                 \
      bf16x8 y0=ld8(a1p+ks*2048), y1=ld8(a1p+ks*2048+512),                       \
             y2=ld8(a1p+ks*2048+1024), y3=ld8(a1p+ks*2048+1536);                 \
      MM16(accA, x0,x1,x2,x3, u0,u1,u2,u3)                                       \
      MM16(accB, y0,y1,y2,y3, v0,v1,v2,v3)                                       \
    } }

#define GEMMC(Abuf, Bgl)                                                         \
  { for (int mt = 0; mt < 4; mt++) for (int nt = 0; nt < 4; nt++)                \
      accA[mt][nt] = (f32x4){0.f,0.f,0.f,0.f};                                   \
    const u16* bptr = (Bgl) + (size_t)(w*64 + l15)*32 + q4*8;                    \
    const u16* ap   = (Abuf) + q4*128 + l15*8;                                   \
    _Pragma("unroll 1")                                                          \
    for (int ks = 0; ks < 16; ks++){                                             \
      bf16x8 u0=ld8(bptr+ks*16384), u1=ld8(bptr+ks*16384+512),                   \
             u2=ld8(bptr+ks*16384+1024), u3=ld8(bptr+ks*16384+1536);             \
      bf16x8 a0=ld8(ap+ks*2048), a1=ld8(ap+ks*2048+512),                         \
             a2=ld8(ap+ks*2048+1024), a3=ld8(ap+ks*2048+1536);                   \
      MM16(accA, a0,a1,a2,a3, u0,u1,u2,u3)                                       \
    } }

#define PROJ_REDUCE                                                              \
  __syncthreads();                                                               \
  if (t < 192){ float s = 0.f;                                                   \
    for (int w2 = 0; w2 < 8; w2++) s += pscr[w2*192 + t];                        \
    totrow[t] += s; }                                                            \
  __syncthreads();

__global__ __launch_bounds__(512, 2) void k_bands3(const u16* canon, const u16* modB,
      const u16* WT, const u16* hlB, const unsigned* flag, void* outv){
  int t = threadIdx.x, rgp = blockIdx.x;
  int lane = t & 63, w = t >> 6, l15 = lane & 15, q4 = lane >> 4;
  __shared__ __align__(16) u16 XL[16*64*32];
  __shared__ __align__(16) u16 AL[16*64*32];
  __shared__ float pscr[1536];
  __shared__ float totrow[192];
  if (t < 192){
    int o = t - (t/3)*3;
    totrow[t] = bs2f(canon[C_OUTB + o]) + bs2f(canon[C_OUTB + 3 + o]) + bs2f(canon[C_OUTB + 6 + o]);
  }
  {
    const u16* src = modB + (size_t)rgp*32768;
    for (int i = 0; i < 8; i++)
      ld2lds(src + i*4096 + w*512 + lane*8, AL + i*4096 + w*512);
  }
  const u16* hl0 = hlB;
  const u16* hl1 = hlB + (size_t)HWQ*512;
  const u16* hl2 = hlB + (size_t)2*HWQ*512;
  int qbase = rgp*8;
  f32x4 accA[4][4], accB[4][4];
  __syncthreads();

  // ---- PHASE A: accA = mod@W0, accB = mod@W1 (shared A) ----
  GEMM2A(AL, WT + MODT_OFF, WT + MODT_OFF + 262144);
  {
    float ow[4][3], b0v[4], b1v[4];
    for (int nt = 0; nt < 4; nt++){
      int c = w*64 + nt*16 + l15;
      b0v[nt] = bs2f(canon[C_MODB + c]);
      b1v[nt] = bs2f(canon[C_MODB + 512 + c]);
      for (int o = 0; o < 3; o++) ow[nt][o] = bs2f(canon[C_OUTW + c*3 + o]);
    }
    for (int mt = 0; mt < 4; mt++) for (int rg = 0; rg < 4; rg++){
      int row = mt*16 + q4*4 + rg;
      int q = qbase + (row >> 3);
      float p0 = 0.f, p1 = 0.f, p2 = 0.f;
      for (int nt = 0; nt < 4; nt++){
        int c = w*64 + nt*16 + l15;
        float v1 = accA[mt][nt][rg] + b0v[nt] + bs2f(hl0[(size_t)q*512 + c]);
        v1 = fmaxf(v1, 0.f);
        float v2 = accB[mt][nt][rg] + b1v[nt] + bs2f(hl1[(size_t)q*512 + c]);
        v2 = fmaxf(v2, 0.f) + v1;
        XL[XLI(row, c)] = f2bs(v2);
        p0 += v1*ow[nt][0]; p1 += v1*ow[nt][1]; p2 += v1*ow[nt][2];
      }
      for (int m = 1; m < 16; m <<= 1){
        p0 += __shfl_xor(p0, m, 64); p1 += __shfl_xor(p1, m, 64); p2 += __shfl_xor(p2, m, 64);
      }
      if (l15 == 0){
        pscr[w*192 + row*3 + 0] = p0;
        pscr[w*192 + row*3 + 1] = p1;
        pscr[w*192 + row*3 + 2] = p2;
      }
    }
  }
  PROJ_REDUCE;

  // ---- PHASE B: accA = X2@hv0, accB = mod@W2 ----
  GEMM2B(XL, WT + HVT_OFF, AL, WT + MODT_OFF + 524288);
  __syncthreads();
  {
    float ow[4][3], hb[4], b2v[4];
    for (int nt = 0; nt < 4; nt++){
      int c = w*64 + nt*16 + l15;
      hb[nt]  = bs2f(canon[C_HVB + c]);
      b2v[nt] = bs2f(canon[C_MODB + 1024 + c]);
      for (int o = 0; o < 3; o++) ow[nt][o] = bs2f(canon[C_OUTW + 1536 + c*3 + o]);
    }
    for (int mt = 0; mt < 4; mt++) for (int rg = 0; rg < 4; rg++){
      int row = mt*16 + q4*4 + rg;
      int q = qbase + (row >> 3);
      float p0 = 0.f, p1 = 0.f, p2 = 0.f;
      for (int nt = 0; nt < 4; nt++){
        int c = w*64 + nt*16 + l15;
        float v3 = fmaxf(accA[mt][nt][rg] + hb[nt], 0.f);
        float v4 = accB[mt][nt][rg] + b2v[nt] + bs2f(hl2[(size_t)q*512 + c]);
        v4 = fmaxf(v4, 0.f) + v3;
        XL[XLI(row, c)] = f2bs(v4);
        p0 += v3*ow[nt][0]; p1 += v3*ow[nt][1]; p2 += v3*ow[nt][2];
      }
      for (int m = 1; m < 16; m <<= 1){
        p0 += __shfl_xor(p0, m, 64); p1 += __shfl_xor(p1, m, 64); p2 += __shfl_xor(p2, m, 64);
      }
      if (l15 == 0){
        pscr[w*192 + row*3 + 0] = p0;
        pscr[w*192 + row*3 + 1] = p1;
        pscr[w*192 + row*3 + 2] = p2;
      }
    }
  }
  PROJ_REDUCE;

  // ---- PHASE C: g5 = X4@hv1 ; proj2 ----
  GEMMC(XL, WT + HVT_OFF + 262144);
  {
    float ow[4][3], hb[4];
    for (int nt = 0; nt < 4; nt++){
      int c = w*64 + nt*16 + l15;
      hb[nt] = bs2f(canon[C_HVB + 512 + c]);
      for (int o = 0; o < 3; o++) ow[nt][o] = bs2f(canon[C_OUTW + 3072 + c*3 + o]);
    }
    for (int mt = 0; mt < 4; mt++) for (int rg = 0; rg < 4; rg++){
      int row = mt*16 + q4*4 + rg;
      float p0 = 0.f, p1 = 0.f, p2 = 0.f;
      for (int nt = 0; nt < 4; nt++){
        float v = fmaxf(accA[mt][nt][rg] + hb[nt], 0.f);
        p0 += v*ow[nt][0]; p1 += v*ow[nt][1]; p2 += v*ow[nt][2];
      }
      for (int m = 1; m < 16; m <<= 1){
        p0 += __shfl_xor(p0, m, 64); p1 += __shfl_xor(p1, m, 64); p2 += __shfl_xor(p2, m, 64);
      }
      if (l15 == 0){
        pscr[w*192 + row*3 + 0] = p0;
        pscr[w*192 + row*3 + 1] = p1;
        pscr[w*192 + row*3 + 2] = p2;
      }
    }
  }
  PROJ_REDUCE;

  // ---- final store ----
  if (t < 192){
    int row = t / 3, o = t - (t/3)*3;
    int gr = rgp*64 + row;
    int b = gr & 7, q = gr >> 3;
    size_t idx = ((size_t)b*HWQ + q)*3 + o;
    if (*flag) ((float*)outv)[idx] = totrow[t];
    else       ((u16*)outv)[idx]   = f2bs(totrow[t]);
  }
}

extern "C" void kernel_launch(void* const* d_in, const int* in_sizes, int n_in,
                              void* d_out, int out_size, void* d_ws, size_t ws_size,
                              hipStream_t stream){
  (void)in_sizes; (void)n_in; (void)out_size;

  u16* wsp   = (u16*)d_ws;
  unsigned* flag = (unsigned*)wsp;
  u16* canon = wsp + 8;
  u16* WT    = canon + CANON_PAD;
  u16* kpart = WT + 1703936;
  u16* vT    = kpart + 262144;
  u16* qvecB = vT + 262144;
  u16* hlB   = qvecB + 2097152;
  u16* modB  = hlB + 25165824;
  if (ws_size < 199773250ULL) return;

  SrcPtrs sp;
  for (int i = 0; i < 16; i++) sp.p[i] = d_in[i];
  const float* xraw = (const float*)d_in[0];

  k_detect <<<1, 256, 0, stream>>>((const u16*)d_in[3], flag);
  k_convert<<<(C_TOTAL + 255)/256, 256, 0, stream>>>(sp, flag, canon);
  k_tr     <<<1664, 256, 0, stream>>>(canon, WT);
  k_kv     <<<2048, 256, 0, stream>>>(canon, kpart, vT);
  k_query  <<<1024, 256, 0, stream>>>(canon, xraw, flag, WT, qvecB, hlB);
  k_attn   <<<4096, 256, 0, stream>>>(canon, xraw, flag, qvecB, kpart, vT, WT, modB);
  k_bands3 <<<2048, 512, 0, stream>>>(canon, modB, WT, hlB, flag, d_out);
}

// Round 18
// 786.595 us; speedup vs baseline: 1.7779x; 1.0321x over previous
//
#include <hip/hip_runtime.h>
#include <math.h>

typedef unsigned short u16;
typedef unsigned int uint;
typedef __bf16 bf16x8 __attribute__((ext_vector_type(8)));
typedef unsigned short u16x8 __attribute__((ext_vector_type(8)));
typedef float f32x4 __attribute__((ext_vector_type(4)));

#define HWQ 16384
#define PI_F 3.14159265358979323846f

// canonical (bf16) input offsets inside ws
#define C_X     0
#define C_TOK   262144
#define C_QW    1310720
#define C_QB    1376256
#define C_WQ    1376768
#define C_WKV   1442304
#define C_WO    1704448
#define C_BO    1769984
#define C_BWW   1770496
#define C_BWB   1967104
#define C_MODW  1968640
#define C_MODB  2755072
#define C_HVW   2756608
#define C_HVB   3280896
#define C_OUTW  3281920
#define C_OUTB  3286528
#define C_TOTAL 3286537
#define CANON_PAD 3286544

// WkvT (K-blocked transpose of Wkv) lives in the dead space after Wkv:
// C_WKV..C_WKV+131071 = Wkv (512x256); C_WKV+131072.. = WkvT (131072 elems)
#define WKVT_OFF (C_WKV + 131072)

// WT (transposed weights) element offsets (relative to WT base)
// ALL regions K-BLOCKED [kblk][col][32]: elem(col,k) at
//   (k>>5)*(N*32) + col*32 + (k&31)   (N = #cols of the region)
#define QWT_OFF  0
#define WQT_OFF  65536
#define WOT_OFF  131072
#define BWT_OFF  196608
#define MODT_OFF 393216
#define HVT_OFF  1179648

struct SrcPtrs { const void* p[16]; };

__device__ __forceinline__ float bs2f(u16 u){
  unsigned v = ((unsigned)u) << 16; float f; __builtin_memcpy(&f, &v, 4); return f;
}
__device__ __forceinline__ u16 f2bs(float f){
  unsigned v; __builtin_memcpy(&v, &f, 4);
  v = (v + 0x7fffu + ((v >> 16) & 1u)) >> 16;
  return (u16)v;
}
__device__ __forceinline__ f32x4 mfma16(bf16x8 a, bf16x8 b, f32x4 c){
  return __builtin_amdgcn_mfma_f32_16x16x32_bf16(a, b, c, 0, 0, 0);
}
__device__ __forceinline__ bf16x8 ld8(const u16* p){ return *(const bf16x8*)p; }
__device__ __forceinline__ void ld2lds(const u16* g, u16* l){
  __builtin_amdgcn_global_load_lds((__attribute__((address_space(1))) const uint*)g,
                                   (__attribute__((address_space(3))) uint*)l, 16, 0, 0);
}

// ---------------- dtype detect ----------------
__global__ void k_detect(const u16* qb_raw, unsigned* flag){
  __shared__ int cnt[256];
  int t = threadIdx.x;
  u16 u = qb_raw[2*t];
  int e = (u >> 7) & 0xFF;
  cnt[t] = (e >= 126) ? 1 : 0;
  __syncthreads();
  for (int s = 128; s > 0; s >>= 1){
    if (t < s) cnt[t] += cnt[t + s];
    __syncthreads();
  }
  if (t == 0) *flag = (cnt[0] >= 16) ? 1u : 0u;
}

// ---------------- convert inputs to canonical bf16 ----------------
__global__ __launch_bounds__(256) void k_convert(SrcPtrs sp, const unsigned* flag, u16* canon){
  const int offs[17] = {C_X,C_TOK,C_QW,C_QB,C_WQ,C_WKV,C_WO,C_BO,C_BWW,C_BWB,
                        C_MODW,C_MODB,C_HVW,C_HVB,C_OUTW,C_OUTB,C_TOTAL};
  int e = blockIdx.x * 256 + threadIdx.x;
  if (e >= C_TOTAL) return;
  int seg = 0;
  for (int i = 1; i < 16; i++) if (e >= offs[i]) seg = i;
  int local = e - offs[seg];
  if (*flag) canon[e] = f2bs(((const float*)sp.p[seg])[local]);
  else       canon[e] = ((const u16*)sp.p[seg])[local];
}

// ---------------- weight transpose: ALL K-blocked [kblk][col][32] ----------------
// bid >= 1664: WkvT (K=512, N=256) into the dead space after Wkv.
__global__ __launch_bounds__(256) void k_tr(const u16* canon, u16* WT){
  __shared__ u16 tile[32][33];
  int bid = blockIdx.x, t = threadIdx.x;
  const u16* src; u16* dst; int K, N, tl;
  if (bid < 384){
    int m = bid >> 6; tl = bid & 63;
    if (m == 0){ src = canon + C_QW;  dst = WT + QWT_OFF; K = 128; N = 512; }
    else if (m == 1){ src = canon + C_WQ; dst = WT + WQT_OFF; K = 512; N = 128; }
    else if (m == 2){ src = canon + C_WO; dst = WT + WOT_OFF; K = 128; N = 512; }
    else { src = canon + C_BWW + (m-3)*65536; dst = WT + BWT_OFF + (m-3)*65536; K = 128; N = 512; }
  } else if (bid < 1152){
    int m = (bid - 384) >> 8; tl = (bid - 384) & 255;
    src = canon + C_MODW + m*262144; dst = WT + MODT_OFF + m*262144; K = 512; N = 512;
  } else if (bid < 1664){
    int m = (bid - 1152) >> 8; tl = (bid - 1152) & 255;
    src = canon + C_HVW + m*262144; dst = WT + HVT_OFF + m*262144; K = 512; N = 512;
  } else {
    tl = bid - 1664;
    src = canon + C_WKV; dst = (u16*)canon + WKVT_OFF; K = 512; N = 256;
  }
  int kt = K >> 5;
  int k0 = (tl % kt) * 32, n0 = (tl / kt) * 32;
  int tx = t & 31, ty = t >> 5;
  for (int r = 0; r < 4; r++)
    tile[ty + r*8][tx] = src[(size_t)(k0 + ty + r*8) * N + n0 + tx];
  __syncthreads();
  u16* d2 = dst + (size_t)(k0 >> 5)*((size_t)N*32);
  for (int r = 0; r < 4; r++)
    d2[(n0 + ty + r*8)*32 + tx] = tile[tx][ty + r*8];
}

// ---------------- kv = tokens @ Wkv (MFMA GEMM) ----------------
// 32 blocks x 64 token-rows; 4 waves x 64 output cols; B from WkvT (contiguous 1KB frags).
// kpart K-blocked over d: per b, elem(kk,d) at (d>>5)*8192 + kk*32 + (d&31)
// vT    K-blocked over kk: per b, elem(d,kk) at (kk>>5)*4096 + d*32 + (kk&31)
__global__ __launch_bounds__(256) void k_kv(const u16* canon, u16* kpart, u16* vT){
  int t = threadIdx.x, r = blockIdx.x;
  int lane = t & 63, w = t >> 6, l15 = lane & 15, q4 = lane >> 4;
  const u16* tok  = canon + C_TOK + (size_t)r*64*512;
  const u16* wkvT = canon + WKVT_OFF;
  f32x4 acc[4][4];
  for (int mt = 0; mt < 4; mt++) for (int nt = 0; nt < 4; nt++) acc[mt][nt] = (f32x4){0.f,0.f,0.f,0.f};
  const u16* bp = wkvT + (w*64 + l15)*32 + q4*8;
  const u16* ap = tok + l15*512 + q4*8;
  #pragma unroll 1
  for (int ks = 0; ks < 16; ks++){
    bf16x8 b0 = ld8(bp + ks*8192 +    0);
    bf16x8 b1 = ld8(bp + ks*8192 +  512);
    bf16x8 b2 = ld8(bp + ks*8192 + 1024);
    bf16x8 b3 = ld8(bp + ks*8192 + 1536);
    for (int mt = 0; mt < 4; mt++){
      bf16x8 af = ld8(ap + mt*16*512 + ks*32);
      acc[mt][0] = mfma16(af, b0, acc[mt][0]);
      acc[mt][1] = mfma16(af, b1, acc[mt][1]);
      acc[mt][2] = mfma16(af, b2, acc[mt][2]);
      acc[mt][3] = mfma16(af, b3, acc[mt][3]);
    }
  }
  int b = (r*64) >> 8;   // 64-row tiles never straddle a 256-row batch
  for (int mt = 0; mt < 4; mt++) for (int nt = 0; nt < 4; nt++){
    int c = w*64 + nt*16 + l15;
    for (int rg = 0; rg < 4; rg++){
      int row = mt*16 + q4*4 + rg;
      int kk = (r*64 + row) & 255;
      float v = acc[mt][nt][rg];
      if (c < 128)
        kpart[(size_t)b*32768 + (c>>5)*8192 + kk*32 + (c&31)] = f2bs(v);
      else {
        int d = c - 128;
        vT[(size_t)b*32768 + (kk>>5)*4096 + d*32 + (kk&31)] = f2bs(v);
      }
    }
  }
}

// ---------------- per-query: gamma -> xq -> qvec ; h_l bands ----------------
__global__ __launch_bounds__(256) void k_query(const u16* canon, const float* xraw,
      const unsigned* flag, const u16* WT, u16* qvecB, u16* hlB){
  int t = threadIdx.x, q0 = blockIdx.x * 16;
  const u16* q_b = canon + C_QB;
  const u16* bw_b= canon + C_BWB;
  int lane = t & 63, wv = t >> 6, l15 = lane & 15, q4 = lane >> 4;
  __shared__ __align__(16) u16 g[16*136];
  __shared__ __align__(16) u16 xql[16*520];
  __shared__ float cco[32];
  __shared__ float omg[32];
  if (t < 32) cco[t] = (*flag) ? xraw[q0*2 + t] : bs2f(canon[C_X + q0*2 + t]);
  if (t < 32) omg[t] = (float)pow(10.0, 1.0 + t * ((2.1072099696478683 - 1.0)/31.0));
  __syncthreads();
  for (int i = 0; i < 8; i++){
    int id = i*256 + t, qi = id >> 7, f = id & 127;
    int d = f >> 6, r = f & 63, fi = r & 31;
    float arg = PI_F * cco[qi*2 + d] * omg[fi];
    g[qi*136 + f] = f2bs((r < 32) ? sinf(arg) : cosf(arg));
  }
  __syncthreads();
  { // xq = relu(g @ q_W + q_b) -> xql
    const u16* Bm = WT + QWT_OFF;
    for (int nt = 0; nt < 8; nt++){
      f32x4 acc = {0.f,0.f,0.f,0.f};
      int c = wv*128 + nt*16 + l15;
      for (int ks = 0; ks < 4; ks++){
        bf16x8 a  = ld8(g + l15*136 + ks*32 + q4*8);
        bf16x8 bb = ld8(Bm + ks*16384 + c*32 + q4*8);
        acc = mfma16(a, bb, acc);
      }
      float qb = bs2f(q_b[c]);
      for (int rg = 0; rg < 4; rg++){
        int row = q4*4 + rg;
        xql[row*520 + c] = f2bs(fmaxf(acc[rg] + qb, 0.f));
      }
    }
  }
  __syncthreads();
  { // qvec = xq @ Wq -> stage in g -> coalesced store
    const u16* Bm = WT + WQT_OFF;
    for (int nh = 0; nh < 2; nh++){
      f32x4 acc = {0.f,0.f,0.f,0.f};
      int c = wv*32 + nh*16 + l15;
      for (int ks = 0; ks < 16; ks++){
        bf16x8 a  = ld8(xql + l15*520 + ks*32 + q4*8);
        bf16x8 bb = ld8(Bm + ks*4096 + c*32 + q4*8);
        acc = mfma16(a, bb, acc);
      }
      for (int rg = 0; rg < 4; rg++)
        g[(q4*4 + rg)*128 + c] = f2bs(acc[rg]);
    }
    __syncthreads();
    {
      int rr = t >> 4, cc = (t & 15)*8;
      *(u16x8*)(qvecB + (size_t)(q0 + rr)*128 + cc) = *(const u16x8*)(g + rr*128 + cc);
    }
  }
  const double LG[3] = {1.2041199826559248, 1.8061799739838869, 2.4082399653118496};
  for (int ib = 0; ib < 3; ib++){
    __syncthreads();
    if (t < 32) omg[t] = (float)pow(10.0, 1.0 + t * ((LG[ib] - 1.0)/31.0));
    __syncthreads();
    for (int i = 0; i < 8; i++){
      int id = i*256 + t, qi = id >> 7, f = id & 127;
      int d = f >> 6, r = f & 63, fi = r & 31;
      float arg = PI_F * cco[qi*2 + d] * omg[fi];
      g[qi*136 + f] = f2bs((r < 32) ? sinf(arg) : cosf(arg));
    }
    __syncthreads();
    const u16* Bm = WT + BWT_OFF + ib*65536;
    for (int nt = 0; nt < 8; nt++){
      f32x4 acc = {0.f,0.f,0.f,0.f};
      int c = wv*128 + nt*16 + l15;
      for (int ks = 0; ks < 4; ks++){
        bf16x8 a  = ld8(g + l15*136 + ks*32 + q4*8);
        bf16x8 bb = ld8(Bm + ks*16384 + c*32 + q4*8);
        acc = mfma16(a, bb, acc);
      }
      float bias = bs2f(bw_b[ib*512 + c]);
      for (int rg = 0; rg < 4; rg++)
        xql[(q4*4 + rg)*520 + c] = f2bs(fmaxf(acc[rg] + bias, 0.f));
    }
    __syncthreads();
    for (int it = 0; it < 4; it++){
      int rr = it*4 + (t >> 6), cc = (t & 63)*8;
      *(u16x8*)(hlB + ((size_t)ib*HWQ + q0 + rr)*512 + cc) = *(const u16x8*)(xql + rr*520 + cc);
    }
  }
}

// ---------------- attention + mod projection v3 (K-blocked operands) ----------------
__global__ __launch_bounds__(256) void k_attn(const u16* canon, const float* xraw,
      const unsigned* flag, const u16* qvecB, const u16* kpart, const u16* vT,
      const u16* WT, u16* modB){
  int t = threadIdx.x;
  int b = blockIdx.x & 7, qt = blockIdx.x >> 3, q0 = qt*32;
  const u16* bo = canon + C_BO;
  int lane = t & 63, wv = t >> 6, l15 = lane & 15, q4 = lane >> 4;
  __shared__ __align__(16) u16 ql[32*136];
  __shared__ __align__(16) u16 sbuf[32*512];   // pl (32x264) during heads; stg (32x512) after
  __shared__ __align__(16) u16 ot[32*136];
  __shared__ float tqs[32];
  __shared__ float rred [128];
  __shared__ float rred2[128];
  for (int i = 0; i < 16; i++){
    int id = i*256 + t, qi = id >> 7, c = id & 127;
    ql[qi*136 + c] = qvecB[(size_t)(q0 + qi)*128 + c];
  }
  if (t < 32){
    float c0, c1;
    if (*flag){ c0 = xraw[(q0+t)*2]; c1 = xraw[(q0+t)*2 + 1]; }
    else { c0 = bs2f(canon[C_X + (q0+t)*2]); c1 = bs2f(canon[C_X + (q0+t)*2 + 1]); }
    int rr = (int)(c0*16.f), cc = (int)(c1*16.f);
    tqs[t] = (float)(rr*16 + cc) * (1.f/256.f);
  }
  __syncthreads();
  u16* pl = sbuf;                               // row stride 264
  for (int h = 0; h < 2; h++){
    f32x4 sac[2][4];
    for (int mt = 0; mt < 2; mt++) for (int nt = 0; nt < 4; nt++) sac[mt][nt] = (f32x4){0.f,0.f,0.f,0.f};
    const u16* kb = kpart + (size_t)b*32768 + h*16384;   // K-blocked over d
    for (int ks = 0; ks < 2; ks++){
      bf16x8 a0 = ld8(ql + l15*136 + h*64 + ks*32 + q4*8);
      bf16x8 a1 = ld8(ql + (16+l15)*136 + h*64 + ks*32 + q4*8);
      for (int nt = 0; nt < 4; nt++){
        int kk = wv*64 + nt*16 + l15;
        bf16x8 bb = ld8(kb + ks*8192 + kk*32 + q4*8);
        sac[0][nt] = mfma16(a0, bb, sac[0][nt]);
        sac[1][nt] = mfma16(a1, bb, sac[1][nt]);
      }
    }
    float pmax[8];
    for (int i = 0; i < 8; i++) pmax[i] = -1e30f;
    for (int mt = 0; mt < 2; mt++) for (int nt = 0; nt < 4; nt++){
      int kk = wv*64 + nt*16 + l15;
      float pos = ((float)kk + 0.5f) * (1.f/256.f);
      for (int rg = 0; rg < 4; rg++){
        int row = mt*16 + q4*4 + rg;
        float dd = tqs[row] - pos;
        float s = sac[mt][nt][rg]*0.125f - 10.f*dd*dd;
        sac[mt][nt][rg] = s;
        pmax[mt*4+rg] = fmaxf(pmax[mt*4+rg], s);
      }
    }
    for (int m = 1; m < 16; m <<= 1)
      for (int i = 0; i < 8; i++) pmax[i] = fmaxf(pmax[i], __shfl_xor(pmax[i], m, 64));
    if (l15 == 0)
      for (int i = 0; i < 8; i++){
        int row = (i>>2)*16 + q4*4 + (i&3);
        rred[wv*32 + row] = pmax[i];
      }
    __syncthreads();
    float gmax[8];
    for (int i = 0; i < 8; i++){
      int row = (i>>2)*16 + q4*4 + (i&3);
      gmax[i] = fmaxf(fmaxf(rred[row], rred[32+row]), fmaxf(rred[64+row], rred[96+row]));
    }
    float psum[8];
    for (int i = 0; i < 8; i++) psum[i] = 0.f;
    for (int mt = 0; mt < 2; mt++) for (int nt = 0; nt < 4; nt++){
      int kk = wv*64 + nt*16 + l15;
      for (int rg = 0; rg < 4; rg++){
        int row = mt*16 + q4*4 + rg;
        float e = expf(sac[mt][nt][rg] - gmax[mt*4+rg]);
        pl[row*264 + kk] = f2bs(e);
        psum[mt*4+rg] += e;
      }
    }
    for (int m = 1; m < 16; m <<= 1)
      for (int i = 0; i < 8; i++) psum[i] += __shfl_xor(psum[i], m, 64);
    if (l15 == 0)
      for (int i = 0; i < 8; i++){
        int row = (i>>2)*16 + q4*4 + (i&3);
        rred2[wv*32 + row] = psum[i];
      }
    __syncthreads();
    float inv[8];
    for (int i = 0; i < 8; i++){
      int row = (i>>2)*16 + q4*4 + (i&3);
      inv[i] = 1.f/(rred2[row] + rred2[32+row] + rred2[64+row] + rred2[96+row]);
    }
    f32x4 oac[2] = {(f32x4){0.f,0.f,0.f,0.f}, (f32x4){0.f,0.f,0.f,0.f}};
    const u16* vb = vT + (size_t)b*32768 + h*2048;   // K-blocked over kk
    int dl = wv*16 + l15;
    for (int ks = 0; ks < 8; ks++){
      bf16x8 a0 = ld8(pl + l15*264 + ks*32 + q4*8);
      bf16x8 a1 = ld8(pl + (16+l15)*264 + ks*32 + q4*8);
      bf16x8 bb = ld8(vb + ks*4096 + dl*32 + q4*8);
      oac[0] = mfma16(a0, bb, oac[0]);
      oac[1] = mfma16(a1, bb, oac[1]);
    }
    for (int mt = 0; mt < 2; mt++) for (int rg = 0; rg < 4; rg++){
      int row = mt*16 + q4*4 + rg;
      ot[row*136 + h*64 + dl] = f2bs(oac[mt][rg] * inv[mt*4+rg]);
    }
  }
  __syncthreads();
  u16* stg = sbuf;                              // row stride 512
  const u16* wob = WT + WOT_OFF;
  for (int nt = 0; nt < 8; nt++){
    f32x4 mac[2] = {(f32x4){0.f,0.f,0.f,0.f}, (f32x4){0.f,0.f,0.f,0.f}};
    int c = wv*128 + nt*16 + l15;
    for (int ks = 0; ks < 4; ks++){
      bf16x8 a0 = ld8(ot + l15*136 + ks*32 + q4*8);
      bf16x8 a1 = ld8(ot + (16+l15)*136 + ks*32 + q4*8);
      bf16x8 bb = ld8(wob + ks*16384 + c*32 + q4*8);
      mac[0] = mfma16(a0, bb, mac[0]);
      mac[1] = mfma16(a1, bb, mac[1]);
    }
    float bv = bs2f(bo[c]);
    for (int mt = 0; mt < 2; mt++) for (int rg = 0; rg < 4; rg++){
      int row = mt*16 + q4*4 + rg;
      stg[row*512 + c] = f2bs(mac[mt][rg] + bv);
    }
  }
  __syncthreads();
  for (int it = 0; it < 8; it++){
    int rr = it*4 + (t >> 6), cc = (t & 63)*8;
    int q = q0 + rr;
    int rgp = q >> 3, r = (q & 7)*8 + b;
    size_t off = (size_t)rgp*32768 + (size_t)(cc >> 5)*2048 + (size_t)(r >> 4)*512
               + (size_t)((cc >> 3) & 3)*128 + (size_t)(r & 15)*8;
    *(u16x8*)(modB + off) = *(const u16x8*)(stg + rr*512 + cc);
  }
}

// ================= k_bands3 v13 (verified best, unchanged): fused dual-GEMM phases =================
#define ZACC2 for (int mt = 0; mt < 4; mt++) for (int nt = 0; nt < 4; nt++){ \
  accA[mt][nt] = (f32x4){0.f,0.f,0.f,0.f}; accB[mt][nt] = (f32x4){0.f,0.f,0.f,0.f}; }

#define XLI(row, c) (((c) >> 5)*2048 + (((row) >> 4))*512 + ((((c) >> 3) & 3))*128 + (((row) & 15))*8 + ((c) & 7))

#define MM16(ACC, A0,A1,A2,A3, B0,B1,B2,B3)                                      \
  ACC[0][0]=mfma16(A0,B0,ACC[0][0]); ACC[0][1]=mfma16(A0,B1,ACC[0][1]);          \
  ACC[0][2]=mfma16(A0,B2,ACC[0][2]); ACC[0][3]=mfma16(A0,B3,ACC[0][3]);          \
  ACC[1][0]=mfma16(A1,B0,ACC[1][0]); ACC[1][1]=mfma16(A1,B1,ACC[1][1]);          \
  ACC[1][2]=mfma16(A1,B2,ACC[1][2]); ACC[1][3]=mfma16(A1,B3,ACC[1][3]);          \
  ACC[2][0]=mfma16(A2,B0,ACC[2][0]); ACC[2][1]=mfma16(A2,B1,ACC[2][1]);          \
  ACC[2][2]=mfma16(A2,B2,ACC[2][2]); ACC[2][3]=mfma16(A2,B3,ACC[2][3]);          \
  ACC[3][0]=mfma16(A3,B0,ACC[3][0]); ACC[3][1]=mfma16(A3,B1,ACC[3][1]);          \
  ACC[3][2]=mfma16(A3,B2,ACC[3][2]); ACC[3][3]=mfma16(A3,B3,ACC[3][3]);

#define GEMM2A(Abuf, Bg0, Bg1)                                                   \
  { ZACC2                                                                        \
    const u16* b0p = (Bg0) + (size_t)(w*64 + l15)*32 + q4*8;                     \
    const u16* b1p = (Bg1) + (size_t)(w*64 + l15)*32 + q4*8;                     \
    const u16* ap  = (Abuf) + q4*128 + l15*8;                                    \
    _Pragma("unroll 1")                                                          \
    for (int ks = 0; ks < 16; ks++){                                             \
      bf16x8 u0=ld8(b0p+ks*16384), u1=ld8(b0p+ks*16384+512),                     \
             u2=ld8(b0p+ks*16384+1024), u3=ld8(b0p+ks*16384+1536);               \
      bf16x8 v0=ld8(b1p+ks*16384), v1=ld8(b1p+ks*16384+512),                     \
             v2=ld8(b1p+ks*16384+1024), v3=ld8(b1p+ks*16384+1536);               \
      bf16x8 a0=ld8(ap+ks*2048), a1=ld8(ap+ks*2048+512),                         \
             a2=ld8(ap+ks*2048+1024), a3=ld8(ap+ks*2048+1536);                   \
      MM16(accA, a0,a1,a2,a3, u0,u1,u2,u3)                                       \
      MM16(accB, a0,a1,a2,a3, v0,v1,v2,v3)                                       \
    } }

#define GEMM2B(Ab0, Bg0, Ab1, Bg1)                                               \
  { ZACC2                                                                        \
    const u16* b0p = (Bg0) + (size_t)(w*64 + l15)*32 + q4*8;                     \
    const u16* b1p = (Bg1) + (size_t)(w*64 + l15)*32 + q4*8;                     \
    const u16* a0p = (Ab0) + q4*128 + l15*8;                                     \
    const u16* a1p = (Ab1) + q4*128 + l15*8;                                     \
    _Pragma("unroll 1")                                                          \
    for (int ks = 0; ks < 16; ks++){                                             \
      bf16x8 u0=ld8(b0p+ks*16384), u1=ld8(b0p+ks*16384+512),                     \
             u2=ld8(b0p+ks*16384+1024), u3=ld8(b0p+ks*16384+1536);               \
      bf16x8 v0=ld8(b1p+ks*16384), v1=ld8(b1p+ks*16384+512),                     \
             v2=ld8(b1p+ks*16384+1024), v3=ld8(b1p+ks*16384+1536);               \
      bf16x8 x0=ld8(a0p+ks*2048), x1=ld8(a0p+ks*2048+512),                       \
             x2=ld8(a0p+ks*2048+1024), x3=ld8(a0p+ks*2048+1536);                 \
      bf16x8 y0=ld8(a1p+ks*2048), y1=ld8(a1p+ks*2048+512),                       \
             y2=ld8(a1p+ks*2048+1024), y3=ld8(a1p+ks*2048+1536);                 \
      MM16(accA, x0,x1,x2,x3, u0,u1,u2,u3)                                       \
      MM16(accB, y0,y1,y2,y3, v0,v1,v2,v3)                                       \
    } }

#define GEMMC(Abuf, Bgl)                                                         \
  { for (int mt = 0; mt < 4; mt++) for (int nt = 0; nt < 4; nt++)                \
      accA[mt][nt] = (f32x4){0.f,0.f,0.f,0.f};                                   \
    const u16* bptr = (Bgl) + (size_t)(w*64 + l15)*32 + q4*8;                    \
    const u16* ap   = (Abuf) + q4*128 + l15*8;                                   \
    _Pragma("unroll 1")                                                          \
    for (int ks = 0; ks < 16; ks++){                                             \
      bf16x8 u0=ld8(bptr+ks*16384), u1=ld8(bptr+ks*16384+512),                   \
             u2=ld8(bptr+ks*16384+1024), u3=ld8(bptr+ks*16384+1536);             \
      bf16x8 a0=ld8(ap+ks*2048), a1=ld8(ap+ks*2048+512),                         \
             a2=ld8(ap+ks*2048+1024), a3=ld8(ap+ks*2048+1536);                   \
      MM16(accA, a0,a1,a2,a3, u0,u1,u2,u3)                                       \
    } }

#define PROJ_REDUCE                                                              \
  __syncthreads();                                                               \
  if (t < 192){ float s = 0.f;                                                   \
    for (int w2 = 0; w2 < 8; w2++) s += pscr[w2*192 + t];                        \
    totrow[t] += s; }                                                            \
  __syncthreads();

__global__ __launch_bounds__(512, 2) void k_bands3(const u16* canon, const u16* modB,
      const u16* WT, const u16* hlB, const unsigned* flag, void* outv){
  int t = threadIdx.x, rgp = blockIdx.x;
  int lane = t & 63, w = t >> 6, l15 = lane & 15, q4 = lane >> 4;
  __shared__ __align__(16) u16 XL[16*64*32];
  __shared__ __align__(16) u16 AL[16*64*32];
  __shared__ float pscr[1536];
  __shared__ float totrow[192];
  if (t < 192){
    int o = t - (t/3)*3;
    totrow[t] = bs2f(canon[C_OUTB + o]) + bs2f(canon[C_OUTB + 3 + o]) + bs2f(canon[C_OUTB + 6 + o]);
  }
  {
    const u16* src = modB + (size_t)rgp*32768;
    for (int i = 0; i < 8; i++)
      ld2lds(src + i*4096 + w*512 + lane*8, AL + i*4096 + w*512);
  }
  const u16* hl0 = hlB;
  const u16* hl1 = hlB + (size_t)HWQ*512;
  const u16* hl2 = hlB + (size_t)2*HWQ*512;
  int qbase = rgp*8;
  f32x4 accA[4][4], accB[4][4];
  __syncthreads();

  // ---- PHASE A: accA = mod@W0, accB = mod@W1 (shared A) ----
  GEMM2A(AL, WT + MODT_OFF, WT + MODT_OFF + 262144);
  {
    float ow[4][3], b0v[4], b1v[4];
    for (int nt = 0; nt < 4; nt++){
      int c = w*64 + nt*16 + l15;
      b0v[nt] = bs2f(canon[C_MODB + c]);
      b1v[nt] = bs2f(canon[C_MODB + 512 + c]);
      for (int o = 0; o < 3; o++) ow[nt][o] = bs2f(canon[C_OUTW + c*3 + o]);
    }
    for (int mt = 0; mt < 4; mt++) for (int rg = 0; rg < 4; rg++){
      int row = mt*16 + q4*4 + rg;
      int q = qbase + (row >> 3);
      float p0 = 0.f, p1 = 0.f, p2 = 0.f;
      for (int nt = 0; nt < 4; nt++){
        int c = w*64 + nt*16 + l15;
        float v1 = accA[mt][nt][rg] + b0v[nt] + bs2f(hl0[(size_t)q*512 + c]);
        v1 = fmaxf(v1, 0.f);
        float v2 = accB[mt][nt][rg] + b1v[nt] + bs2f(hl1[(size_t)q*512 + c]);
        v2 = fmaxf(v2, 0.f) + v1;
        XL[XLI(row, c)] = f2bs(v2);
        p0 += v1*ow[nt][0]; p1 += v1*ow[nt][1]; p2 += v1*ow[nt][2];
      }
      for (int m = 1; m < 16; m <<= 1){
        p0 += __shfl_xor(p0, m, 64); p1 += __shfl_xor(p1, m, 64); p2 += __shfl_xor(p2, m, 64);
      }
      if (l15 == 0){
        pscr[w*192 + row*3 + 0] = p0;
        pscr[w*192 + row*3 + 1] = p1;
        pscr[w*192 + row*3 + 2] = p2;
      }
    }
  }
  PROJ_REDUCE;

  // ---- PHASE B: accA = X2@hv0, accB = mod@W2 ----
  GEMM2B(XL, WT + HVT_OFF, AL, WT + MODT_OFF + 524288);
  __syncthreads();
  {
    float ow[4][3], hb[4], b2v[4];
    for (int nt = 0; nt < 4; nt++){
      int c = w*64 + nt*16 + l15;
      hb[nt]  = bs2f(canon[C_HVB + c]);
      b2v[nt] = bs2f(canon[C_MODB + 1024 + c]);
      for (int o = 0; o < 3; o++) ow[nt][o] = bs2f(canon[C_OUTW + 1536 + c*3 + o]);
    }
    for (int mt = 0; mt < 4; mt++) for (int rg = 0; rg < 4; rg++){
      int row = mt*16 + q4*4 + rg;
      int q = qbase + (row >> 3);
      float p0 = 0.f, p1 = 0.f, p2 = 0.f;
      for (int nt = 0; nt < 4; nt++){
        int c = w*64 + nt*16 + l15;
        float v3 = fmaxf(accA[mt][nt][rg] + hb[nt], 0.f);
        float v4 = accB[mt][nt][rg] + b2v[nt] + bs2f(hl2[(size_t)q*512 + c]);
        v4 = fmaxf(v4, 0.f) + v3;
        XL[XLI(row, c)] = f2bs(v4);
        p0 += v3*ow[nt][0]; p1 += v3*ow[nt][1]; p2 += v3*ow[nt][2];
      }
      for (int m = 1; m < 16; m <<= 1){
        p0 += __shfl_xor(p0, m, 64); p1 += __shfl_xor(p1, m, 64); p2 += __shfl_xor(p2, m, 64);
      }
      if (l15 == 0){
        pscr[w*192 + row*3 + 0] = p0;
        pscr[w*192 + row*3 + 1] = p1;
        pscr[w*192 + row*3 + 2] = p2;
      }
    }
  }
  PROJ_REDUCE;

  // ---- PHASE C: g5 = X4@hv1 ; proj2 ----
  GEMMC(XL, WT + HVT_OFF + 262144);
  {
    float ow[4][3], hb[4];
    for (int nt = 0; nt < 4; nt++){
      int c = w*64 + nt*16 + l15;
      hb[nt] = bs2f(canon[C_HVB + 512 + c]);
      for (int o = 0; o < 3; o++) ow[nt][o] = bs2f(canon[C_OUTW + 3072 + c*3 + o]);
    }
    for (int mt = 0; mt < 4; mt++) for (int rg = 0; rg < 4; rg++){
      int row = mt*16 + q4*4 + rg;
      float p0 = 0.f, p1 = 0.f, p2 = 0.f;
      for (int nt = 0; nt < 4; nt++){
        float v = fmaxf(accA[mt][nt][rg] + hb[nt], 0.f);
        p0 += v*ow[nt][0]; p1 += v*ow[nt][1]; p2 += v*ow[nt][2];
      }
      for (int m = 1; m < 16; m <<= 1){
        p0 += __shfl_xor(p0, m, 64); p1 += __shfl_xor(p1, m, 64); p2 += __shfl_xor(p2, m, 64);
      }
      if (l15 == 0){
        pscr[w*192 + row*3 + 0] = p0;
        pscr[w*192 + row*3 + 1] = p1;
        pscr[w*192 + row*3 + 2] = p2;
      }
    }
  }
  PROJ_REDUCE;

  // ---- final store ----
  if (t < 192){
    int row = t / 3, o = t - (t/3)*3;
    int gr = rgp*64 + row;
    int b = gr & 7, q = gr >> 3;
    size_t idx = ((size_t)b*HWQ + q)*3 + o;
    if (*flag) ((float*)outv)[idx] = totrow[t];
    else       ((u16*)outv)[idx]   = f2bs(totrow[t]);
  }
}

extern "C" void kernel_launch(void* const* d_in, const int* in_sizes, int n_in,
                              void* d_out, int out_size, void* d_ws, size_t ws_size,
                              hipStream_t stream){
  (void)in_sizes; (void)n_in; (void)out_size;

  u16* wsp   = (u16*)d_ws;
  unsigned* flag = (unsigned*)wsp;
  u16* canon = wsp + 8;
  u16* WT    = canon + CANON_PAD;
  u16* kpart = WT + 1703936;
  u16* vT    = kpart + 262144;
  u16* qvecB = vT + 262144;
  u16* hlB   = qvecB + 2097152;
  u16* modB  = hlB + 25165824;
  if (ws_size < 199773250ULL) return;

  SrcPtrs sp;
  for (int i = 0; i < 16; i++) sp.p[i] = d_in[i];
  const float* xraw = (const float*)d_in[0];

  k_detect <<<1, 256, 0, stream>>>((const u16*)d_in[3], flag);
  k_convert<<<(C_TOTAL + 255)/256, 256, 0, stream>>>(sp, flag, canon);
  k_tr     <<<1792, 256, 0, stream>>>(canon, WT);
  k_kv     <<<32, 256, 0, stream>>>(canon, kpart, vT);
  k_query  <<<1024, 256, 0, stream>>>(canon, xraw, flag, WT, qvecB, hlB);
  k_attn   <<<4096, 256, 0, stream>>>(canon, xraw, flag, qvecB, kpart, vT, WT, modB);
  k_bands3 <<<2048, 512, 0, stream>>>(canon, modB, WT, hlB, flag, d_out);
}